// Round 4
// baseline (2000.139 us; speedup 1.0000x reference)
//
#include <hip/hip_runtime.h>
#include <hip/hip_bf16.h>

#define NB 256
#define NL 64
#define DEG 6
#define FEAT 39
#define BOND 10
#define FP 256
#define NEGV (-9.0e8f)

__device__ __forceinline__ float block_sum256(float v, float* scr){
  #pragma unroll
  for(int o=32;o>0;o>>=1) v += __shfl_down(v, o, 64);
  __syncthreads();
  if((threadIdx.x & 63) == 0) scr[threadIdx.x >> 6] = v;
  __syncthreads();
  return scr[0] + scr[1] + scr[2] + scr[3];
}

// ---------------- K1: atom_feature = leaky(atom_list @ atom_fc_w.T + b) ----------------
__global__ void k_atom_fc(const float* __restrict__ atom, const float* __restrict__ W,
                          const float* __restrict__ bias, float* __restrict__ af){
  const int row = blockIdx.x;
  const int t = threadIdx.x;
  __shared__ float x[FEAT];
  if(t < FEAT) x[t] = atom[row*FEAT + t];
  __syncthreads();
  float acc = bias[t];
  const float* wr = W + t*FEAT;
  #pragma unroll
  for(int k=0;k<FEAT;++k) acc = fmaf(x[k], wr[k], acc);
  af[row*FP + t] = acc > 0.f ? acc : 0.01f*acc;
}

// ------- K2: fused neighbor_fc + align(d=0) + softmax + weighted neighbor sum -------
__global__ void k_nbr_align(const float* __restrict__ atom, const float* __restrict__ bond,
    const int* __restrict__ adl, const int* __restrict__ bdl,
    const float* __restrict__ Wn, const float* __restrict__ bn,
    const float* __restrict__ alw, const float* __restrict__ alb,
    const float* __restrict__ af, float* __restrict__ wnf, float* __restrict__ swb){
  const int bl = blockIdx.x;        // b*NL + l
  const int b  = bl >> 6;
  const int t  = threadIdx.x;
  __shared__ float in_s[DEG][FEAT+BOND];
  __shared__ float nf_s[DEG][FP];
  __shared__ float af_s[FP];
  __shared__ int   ai[DEG];
  __shared__ float msk[DEG];
  __shared__ float sc[DEG];
  __shared__ float scr[4];
  if(t < DEG){ int a = adl[bl*DEG + t]; ai[t] = a; msk[t] = (a == NL-1) ? 0.f : 1.f; }
  af_s[t] = af[bl*FP + t];
  __syncthreads();
  for(int idx = t; idx < DEG*(FEAT+BOND); idx += FP){
    int d = idx / (FEAT+BOND), k = idx % (FEAT+BOND);
    float v;
    if(k < FEAT) v = atom[(b*NL + ai[d])*FEAT + k];
    else { int bi = bdl[bl*DEG + d]; v = bond[(b*NL + bi)*BOND + (k-FEAT)]; }
    in_s[d][k] = v;
  }
  __syncthreads();
  float acc[DEG];
  #pragma unroll
  for(int d=0;d<DEG;++d) acc[d] = 0.f;
  const float* wr = Wn + t*(FEAT+BOND);
  for(int k=0;k<FEAT+BOND;++k){
    float w = wr[k];
    #pragma unroll
    for(int d=0;d<DEG;++d) acc[d] = fmaf(in_s[d][k], w, acc[d]);
  }
  float bv = bn[t];
  #pragma unroll
  for(int d=0;d<DEG;++d){
    float v = acc[d] + bv;
    nf_s[d][t] = v > 0.f ? v : 0.01f*v;
  }
  __syncthreads();
  float aw1 = alw[t], aw2 = alw[FP + t];
  float sa = block_sum256(aw1*af_s[t], scr);
  float ab = alb[0];
  for(int d=0;d<DEG;++d){
    float s = block_sum256(aw2*nf_s[d][t], scr);
    if(t==0){
      float v = sa + s + ab;
      v = v > 0.f ? v : 0.01f*v;
      sc[d] = v + (msk[d] > 0.f ? 0.f : NEGV);
    }
  }
  __syncthreads();
  float m = sc[0];
  #pragma unroll
  for(int d=1;d<DEG;++d) m = fmaxf(m, sc[d]);
  float e[DEG], Z = 0.f;
  #pragma unroll
  for(int d=0;d<DEG;++d){ e[d] = expf(sc[d]-m); Z += e[d]; }
  float w_[DEG], sw = 0.f;
  #pragma unroll
  for(int d=0;d<DEG;++d){ w_[d] = e[d]/Z*msk[d]; sw += w_[d]; }
  float o = 0.f;
  #pragma unroll
  for(int d=0;d<DEG;++d) o = fmaf(w_[d], nf_s[d][t], o);
  wnf[bl*FP + t] = o;
  if(t==0) swb[bl] = sw;
}

// ---- K3: context = elu(x@Wat.T + swb*bat); af = GRU(context, af). 16 rows/block ----
template<int RELUX>
__global__ __launch_bounds__(256) void k_ctx_gru(
    const float* __restrict__ xsrc, const float* __restrict__ swb, float* __restrict__ af,
    const float* __restrict__ Wat, const float* __restrict__ bat,
    const float* __restrict__ wih, const float* __restrict__ whh,
    const float* __restrict__ bih, const float* __restrict__ bhh){
  const int R = 16;
  const int row0 = blockIdx.x * R;
  const int t = threadIdx.x;
  __shared__ __align__(16) float x_s[R][FP];
  __shared__ __align__(16) float h_s[R][FP];
  __shared__ float swb_s[R];
  if(t < R) swb_s[t] = swb[row0 + t];
  __syncthreads();
  #pragma unroll
  for(int r=0;r<R;++r){
    float h = af[(size_t)(row0+r)*FP + t];
    h_s[r][t] = h;
    if(RELUX) x_s[r][t] = fmaxf(h, 0.f) * swb_s[r];
    else      x_s[r][t] = xsrc[(size_t)(row0+r)*FP + t];
  }
  __syncthreads();
  // phase 1: attend matmul -> context
  float acc[R];
  #pragma unroll
  for(int r=0;r<R;++r) acc[r] = 0.f;
  const float4* wr = (const float4*)(Wat + (size_t)t*FP);
  for(int k4=0;k4<FP/4;++k4){
    float4 w = wr[k4];
    #pragma unroll
    for(int r=0;r<R;++r){
      float4 xv = ((const float4*)x_s[r])[k4];
      acc[r] = fmaf(xv.x,w.x,acc[r]); acc[r] = fmaf(xv.y,w.y,acc[r]);
      acc[r] = fmaf(xv.z,w.z,acc[r]); acc[r] = fmaf(xv.w,w.w,acc[r]);
    }
  }
  float batv = bat[t];
  float ctx[R];
  #pragma unroll
  for(int r=0;r<R;++r){
    float pre = acc[r] + swb_s[r]*batv;
    ctx[r] = pre > 0.f ? pre : expm1f(pre);
  }
  __syncthreads();
  #pragma unroll
  for(int r=0;r<R;++r) x_s[r][t] = ctx[r];   // x_s now holds context
  __syncthreads();
  // phase 2a: input-side gates over ctx
  float ar_[R], az_[R], an_[R];
  #pragma unroll
  for(int r=0;r<R;++r){ ar_[r]=0.f; az_[r]=0.f; an_[r]=0.f; }
  {
    const float4* p0 = (const float4*)(wih + (size_t)t*FP);
    const float4* p1 = (const float4*)(wih + (size_t)(FP+t)*FP);
    const float4* p2 = (const float4*)(wih + (size_t)(2*FP+t)*FP);
    for(int k4=0;k4<FP/4;++k4){
      float4 w0=p0[k4], w1=p1[k4], w2=p2[k4];
      #pragma unroll
      for(int r=0;r<R;++r){
        float4 xv = ((const float4*)x_s[r])[k4];
        ar_[r]=fmaf(xv.x,w0.x,ar_[r]); ar_[r]=fmaf(xv.y,w0.y,ar_[r]);
        ar_[r]=fmaf(xv.z,w0.z,ar_[r]); ar_[r]=fmaf(xv.w,w0.w,ar_[r]);
        az_[r]=fmaf(xv.x,w1.x,az_[r]); az_[r]=fmaf(xv.y,w1.y,az_[r]);
        az_[r]=fmaf(xv.z,w1.z,az_[r]); az_[r]=fmaf(xv.w,w1.w,az_[r]);
        an_[r]=fmaf(xv.x,w2.x,an_[r]); an_[r]=fmaf(xv.y,w2.y,an_[r]);
        an_[r]=fmaf(xv.z,w2.z,an_[r]); an_[r]=fmaf(xv.w,w2.w,an_[r]);
      }
    }
  }
  // phase 2b: hidden-side gates over h
  float hr_[R], hz_[R], hn_[R];
  #pragma unroll
  for(int r=0;r<R;++r){ hr_[r]=0.f; hz_[r]=0.f; hn_[r]=0.f; }
  {
    const float4* p0 = (const float4*)(whh + (size_t)t*FP);
    const float4* p1 = (const float4*)(whh + (size_t)(FP+t)*FP);
    const float4* p2 = (const float4*)(whh + (size_t)(2*FP+t)*FP);
    for(int k4=0;k4<FP/4;++k4){
      float4 w0=p0[k4], w1=p1[k4], w2=p2[k4];
      #pragma unroll
      for(int r=0;r<R;++r){
        float4 hv = ((const float4*)h_s[r])[k4];
        hr_[r]=fmaf(hv.x,w0.x,hr_[r]); hr_[r]=fmaf(hv.y,w0.y,hr_[r]);
        hr_[r]=fmaf(hv.z,w0.z,hr_[r]); hr_[r]=fmaf(hv.w,w0.w,hr_[r]);
        hz_[r]=fmaf(hv.x,w1.x,hz_[r]); hz_[r]=fmaf(hv.y,w1.y,hz_[r]);
        hz_[r]=fmaf(hv.z,w1.z,hz_[r]); hz_[r]=fmaf(hv.w,w1.w,hz_[r]);
        hn_[r]=fmaf(hv.x,w2.x,hn_[r]); hn_[r]=fmaf(hv.y,w2.y,hn_[r]);
        hn_[r]=fmaf(hv.z,w2.z,hn_[r]); hn_[r]=fmaf(hv.w,w2.w,hn_[r]);
      }
    }
  }
  float bir = bih[t], biz = bih[FP+t], bin_ = bih[2*FP+t];
  float bhr = bhh[t], bhz = bhh[FP+t], bhn  = bhh[2*FP+t];
  #pragma unroll
  for(int r=0;r<R;++r){
    float ir = ar_[r]+bir, iz = az_[r]+biz, inn = an_[r]+bin_;
    float hr = hr_[r]+bhr, hz = hz_[r]+bhz, hn  = hn_[r]+bhn;
    float rg = 1.f/(1.f + expf(-(ir+hr)));
    float zg = 1.f/(1.f + expf(-(iz+hz)));
    float ng = tanhf(inn + rg*hn);
    af[(size_t)(row0+r)*FP + t] = (1.f-zg)*ng + zg*h_s[r][t];
  }
}

// ---- K4: attended_mol = af@maw.T + mab; molfeat = sum relu(af)*mask; emit af f32 ----
__global__ void k_mol_att(const float* __restrict__ af, const float* __restrict__ maw,
    const float* __restrict__ mab, const float* __restrict__ mask,
    float* __restrict__ att, float* __restrict__ molfeat, float* __restrict__ out_af){
  const int b = blockIdx.x, t = threadIdx.x;
  __shared__ __align__(16) float a_s[32][FP];
  __shared__ float msk_s[NL];
  if(t < NL) msk_s[t] = mask[b*NL + t];
  __syncthreads();
  float mf = 0.f;
  const float4* wr = (const float4*)(maw + (size_t)t*FP);
  float mabv = mab[t];
  for(int half=0; half<2; ++half){
    #pragma unroll
    for(int i=0;i<32;++i){
      int l = half*32 + i;
      float v = af[(size_t)(b*NL + l)*FP + t];
      a_s[i][t] = v;
      out_af[(size_t)(b*NL + l)*FP + t] = v;   // f32 final output
      mf = fmaf(fmaxf(v,0.f), msk_s[l], mf);
    }
    __syncthreads();
    float acc[32];
    #pragma unroll
    for(int i=0;i<32;++i) acc[i] = 0.f;
    for(int k4=0;k4<FP/4;++k4){
      float4 w = wr[k4];
      #pragma unroll
      for(int i=0;i<32;++i){
        float4 xv = ((const float4*)a_s[i])[k4];
        acc[i] = fmaf(xv.x,w.x,acc[i]); acc[i] = fmaf(xv.y,w.y,acc[i]);
        acc[i] = fmaf(xv.z,w.z,acc[i]); acc[i] = fmaf(xv.w,w.w,acc[i]);
      }
    }
    #pragma unroll
    for(int i=0;i<32;++i) att[(size_t)(b*NL + half*32 + i)*FP + t] = acc[i] + mabv;
    __syncthreads();
  }
  molfeat[b*FP + t] = mf;
}

// ---------------- K5: one mol attention + GRU step (block per molecule) ----------------
__global__ void k_mol_step(const float* __restrict__ af, const float* __restrict__ att,
    float* __restrict__ molfeat, const float* __restrict__ maw, const float* __restrict__ mabp,
    const float* __restrict__ mask,
    const float* __restrict__ wih, const float* __restrict__ whh,
    const float* __restrict__ bih, const float* __restrict__ bhh){
  const int b = blockIdx.x, t = threadIdx.x;
  __shared__ __align__(16) float mf_s[FP];
  __shared__ __align__(16) float ctx_s[FP];
  __shared__ float sc_s[NL], aw_s[NL], scr[4];
  mf_s[t] = molfeat[b*FP + t];
  __syncthreads();
  float sa = block_sum256(maw[t]*mf_s[t], scr);
  int l = t >> 2, q = t & 3;
  float p = 0.f;
  {
    const float* ar = af + (size_t)(b*NL + l)*FP + q*64;
    const float* w2 = maw + FP + q*64;
    for(int k=0;k<64;++k) p = fmaf(ar[k], w2[k], p);
  }
  p += __shfl_xor(p, 1, 64);
  p += __shfl_xor(p, 2, 64);
  if(q == 0){
    float mv = mask[b*NL + l];
    float v = sa + p + mabp[0];
    v = v > 0.f ? v : 0.01f*v;
    sc_s[l] = v + (mv == 0.f ? NEGV : 0.f);
  }
  __syncthreads();
  if(t < NL){
    float s = sc_s[t];
    float m = s;
    #pragma unroll
    for(int o=32;o>0;o>>=1) m = fmaxf(m, __shfl_xor(m, o, 64));
    float e = expf(s - m);
    float Z = e;
    #pragma unroll
    for(int o=32;o>0;o>>=1) Z += __shfl_xor(Z, o, 64);
    aw_s[t] = e / Z * mask[b*NL + t];
  }
  __syncthreads();
  float acc = 0.f;
  for(int l2=0;l2<NL;++l2) acc = fmaf(aw_s[l2], att[(size_t)(b*NL + l2)*FP + t], acc);
  ctx_s[t] = acc > 0.f ? acc : expm1f(acc);
  __syncthreads();
  float air=0.f, aiz=0.f, ain=0.f, ahr=0.f, ahz=0.f, ahn=0.f;
  const float4* wirp=(const float4*)(wih + (size_t)t*FP);
  const float4* wizp=(const float4*)(wih + (size_t)(FP+t)*FP);
  const float4* winp=(const float4*)(wih + (size_t)(2*FP+t)*FP);
  const float4* whrp=(const float4*)(whh + (size_t)t*FP);
  const float4* whzp=(const float4*)(whh + (size_t)(FP+t)*FP);
  const float4* whnp=(const float4*)(whh + (size_t)(2*FP+t)*FP);
  for(int k4=0;k4<FP/4;++k4){
    float4 xv = ((const float4*)ctx_s)[k4];
    float4 hv = ((const float4*)mf_s)[k4];
    float4 f0=wirp[k4], f1=wizp[k4], f2=winp[k4];
    float4 g0=whrp[k4], g1=whzp[k4], g2=whnp[k4];
    air=fmaf(xv.x,f0.x,air); air=fmaf(xv.y,f0.y,air); air=fmaf(xv.z,f0.z,air); air=fmaf(xv.w,f0.w,air);
    aiz=fmaf(xv.x,f1.x,aiz); aiz=fmaf(xv.y,f1.y,aiz); aiz=fmaf(xv.z,f1.z,aiz); aiz=fmaf(xv.w,f1.w,aiz);
    ain=fmaf(xv.x,f2.x,ain); ain=fmaf(xv.y,f2.y,ain); ain=fmaf(xv.z,f2.z,ain); ain=fmaf(xv.w,f2.w,ain);
    ahr=fmaf(hv.x,g0.x,ahr); ahr=fmaf(hv.y,g0.y,ahr); ahr=fmaf(hv.z,g0.z,ahr); ahr=fmaf(hv.w,g0.w,ahr);
    ahz=fmaf(hv.x,g1.x,ahz); ahz=fmaf(hv.y,g1.y,ahz); ahz=fmaf(hv.z,g1.z,ahz); ahz=fmaf(hv.w,g1.w,ahz);
    ahn=fmaf(hv.x,g2.x,ahn); ahn=fmaf(hv.y,g2.y,ahn); ahn=fmaf(hv.z,g2.z,ahn); ahn=fmaf(hv.w,g2.w,ahn);
  }
  float ir=air+bih[t], iz=aiz+bih[FP+t], inn=ain+bih[2*FP+t];
  float hr=ahr+bhh[t], hz=ahz+bhh[FP+t], hn=ahn+bhh[2*FP+t];
  float rg = 1.f/(1.f + expf(-(ir+hr)));
  float zg = 1.f/(1.f + expf(-(iz+hz)));
  float ng = tanhf(inn + rg*hn);
  molfeat[b*FP + t] = (1.f-zg)*ng + zg*mf_s[t];
}

// ---------------- K6: mol_prediction (f32 out) ----------------
__global__ void k_out(const float* __restrict__ molfeat, const float* __restrict__ ow,
                      const float* __restrict__ ob, float* __restrict__ outp){
  const int b = blockIdx.x, t = threadIdx.x;
  __shared__ float scr[4];
  float s = block_sum256(molfeat[b*FP + t]*ow[t], scr);
  if(t == 0) outp[b] = s + ob[0];
}

extern "C" void kernel_launch(void* const* d_in, const int* in_sizes, int n_in,
                              void* d_out, int out_size, void* d_ws, size_t ws_size,
                              hipStream_t stream){
  const float* atom_list = (const float*)d_in[0];
  const float* bond_list = (const float*)d_in[1];
  const int*   adl       = (const int*)d_in[2];
  const int*   bdl       = (const int*)d_in[3];
  const float* amask     = (const float*)d_in[4];
  const float* afc_w     = (const float*)d_in[5];
  const float* afc_b     = (const float*)d_in[6];
  const float* nfc_w     = (const float*)d_in[7];
  const float* nfc_b     = (const float*)d_in[8];
  const float* align_w   = (const float*)d_in[9];
  const float* align_b   = (const float*)d_in[10];
  const float* attend_w  = (const float*)d_in[11];
  const float* attend_b  = (const float*)d_in[12];
  const float* gru_wih   = (const float*)d_in[13];
  const float* gru_whh   = (const float*)d_in[14];
  const float* gru_bih   = (const float*)d_in[15];
  const float* gru_bhh   = (const float*)d_in[16];
  const float* mol_align_w  = (const float*)d_in[17];
  const float* mol_align_b  = (const float*)d_in[18];
  const float* mol_attend_w = (const float*)d_in[19];
  const float* mol_attend_b = (const float*)d_in[20];
  const float* mg_wih    = (const float*)d_in[21];
  const float* mg_whh    = (const float*)d_in[22];
  const float* mg_bih    = (const float*)d_in[23];
  const float* mg_bhh    = (const float*)d_in[24];
  const float* out_w     = (const float*)d_in[25];
  const float* out_b     = (const float*)d_in[26];

  float* af      = (float*)d_ws;                       // [16384,256] f32
  float* wnf     = af  + (size_t)NB*NL*FP;             // [16384,256] (reused as attended_mol)
  float* swb     = wnf + (size_t)NB*NL*FP;             // [16384]
  float* molfeat = swb + (size_t)NB*NL;                // [256,256]

  float* out_af   = (float*)d_out;                     // f32 final outputs
  float* out_pred = out_af + (size_t)NB*NL*FP;

  k_atom_fc<<<NB*NL, FP, 0, stream>>>(atom_list, afc_w, afc_b, af);
  k_nbr_align<<<NB*NL, FP, 0, stream>>>(atom_list, bond_list, adl, bdl,
                                        nfc_w, nfc_b, align_w, align_b, af, wnf, swb);
  for(int d=0; d<3; ++d){
    const float* Wat = attend_w + (size_t)d*FP*FP;
    const float* bat = attend_b + (size_t)d*FP;
    const float* wih = gru_wih + (size_t)d*3*FP*FP;
    const float* whh = gru_whh + (size_t)d*3*FP*FP;
    const float* bih = gru_bih + (size_t)d*3*FP;
    const float* bhh = gru_bhh + (size_t)d*3*FP;
    if(d == 0) k_ctx_gru<0><<<NB*NL/16, FP, 0, stream>>>(wnf, swb, af, Wat, bat, wih, whh, bih, bhh);
    else       k_ctx_gru<1><<<NB*NL/16, FP, 0, stream>>>(af,  swb, af, Wat, bat, wih, whh, bih, bhh);
  }
  k_mol_att<<<NB, FP, 0, stream>>>(af, mol_attend_w, mol_attend_b, amask, wnf, molfeat, out_af);
  for(int s=0; s<2; ++s)
    k_mol_step<<<NB, FP, 0, stream>>>(af, wnf, molfeat, mol_align_w, mol_align_b, amask,
                                      mg_wih, mg_whh, mg_bih, mg_bhh);
  k_out<<<NB, FP, 0, stream>>>(molfeat, out_w, out_b, out_pred);
}

// Round 5
// 639.570 us; speedup vs baseline: 3.1273x; 3.1273x over previous
//
#include <hip/hip_runtime.h>
#include <hip/hip_bf16.h>

#define NB 256
#define NL 64
#define DEG 6
#define FEAT 39
#define BOND 10
#define FP 256
#define NEGV (-9.0e8f)

using s16x8 = __attribute__((ext_vector_type(8))) short;
using f32x4 = __attribute__((ext_vector_type(4))) float;

__device__ __forceinline__ unsigned short f2bf(float f){
  unsigned u = __float_as_uint(f);
  u += 0x7fffu + ((u >> 16) & 1u);      // RNE
  return (unsigned short)(u >> 16);
}

__device__ __forceinline__ float block_sum256(float v, float* scr){
  #pragma unroll
  for(int o=32;o>0;o>>=1) v += __shfl_down(v, o, 64);
  __syncthreads();
  if((threadIdx.x & 63) == 0) scr[threadIdx.x >> 6] = v;
  __syncthreads();
  return scr[0] + scr[1] + scr[2] + scr[3];
}

// ---------------- weight f32 -> bf16 convert ----------------
__global__ void k_cvt(const float* __restrict__ src, unsigned short* __restrict__ dst, int n){
  int i = blockIdx.x*256 + threadIdx.x;
  if(i < n) dst[i] = f2bf(src[i]);
}

// ---------------- K1: atom_feature = leaky(atom_list @ atom_fc_w.T + b) ----------------
__global__ void k_atom_fc(const float* __restrict__ atom, const float* __restrict__ W,
                          const float* __restrict__ bias, float* __restrict__ af){
  const int row = blockIdx.x;
  const int t = threadIdx.x;
  __shared__ float x[FEAT];
  if(t < FEAT) x[t] = atom[row*FEAT + t];
  __syncthreads();
  float acc = bias[t];
  const float* wr = W + t*FEAT;
  #pragma unroll
  for(int k=0;k<FEAT;++k) acc = fmaf(x[k], wr[k], acc);
  af[row*FP + t] = acc > 0.f ? acc : 0.01f*acc;
}

// ------- K2: fused neighbor_fc + align(d=0) + softmax + weighted neighbor sum -------
__global__ void k_nbr_align(const float* __restrict__ atom, const float* __restrict__ bond,
    const int* __restrict__ adl, const int* __restrict__ bdl,
    const float* __restrict__ Wn, const float* __restrict__ bn,
    const float* __restrict__ alw, const float* __restrict__ alb,
    const float* __restrict__ af, float* __restrict__ wnf, float* __restrict__ swb){
  const int bl = blockIdx.x;
  const int b  = bl >> 6;
  const int t  = threadIdx.x;
  __shared__ float in_s[DEG][FEAT+BOND];
  __shared__ float nf_s[DEG][FP];
  __shared__ float af_s[FP];
  __shared__ int   ai[DEG];
  __shared__ float msk[DEG];
  __shared__ float sc[DEG];
  __shared__ float scr[4];
  if(t < DEG){ int a = adl[bl*DEG + t]; ai[t] = a; msk[t] = (a == NL-1) ? 0.f : 1.f; }
  af_s[t] = af[bl*FP + t];
  __syncthreads();
  for(int idx = t; idx < DEG*(FEAT+BOND); idx += FP){
    int d = idx / (FEAT+BOND), k = idx % (FEAT+BOND);
    float v;
    if(k < FEAT) v = atom[(b*NL + ai[d])*FEAT + k];
    else { int bi = bdl[bl*DEG + d]; v = bond[(b*NL + bi)*BOND + (k-FEAT)]; }
    in_s[d][k] = v;
  }
  __syncthreads();
  float acc[DEG];
  #pragma unroll
  for(int d=0;d<DEG;++d) acc[d] = 0.f;
  const float* wr = Wn + t*(FEAT+BOND);
  for(int k=0;k<FEAT+BOND;++k){
    float w = wr[k];
    #pragma unroll
    for(int d=0;d<DEG;++d) acc[d] = fmaf(in_s[d][k], w, acc[d]);
  }
  float bv = bn[t];
  #pragma unroll
  for(int d=0;d<DEG;++d){
    float v = acc[d] + bv;
    nf_s[d][t] = v > 0.f ? v : 0.01f*v;
  }
  __syncthreads();
  float aw1 = alw[t], aw2 = alw[FP + t];
  float sa = block_sum256(aw1*af_s[t], scr);
  float ab = alb[0];
  for(int d=0;d<DEG;++d){
    float s = block_sum256(aw2*nf_s[d][t], scr);
    if(t==0){
      float v = sa + s + ab;
      v = v > 0.f ? v : 0.01f*v;
      sc[d] = v + (msk[d] > 0.f ? 0.f : NEGV);
    }
  }
  __syncthreads();
  float m = sc[0];
  #pragma unroll
  for(int d=1;d<DEG;++d) m = fmaxf(m, sc[d]);
  float e[DEG], Z = 0.f;
  #pragma unroll
  for(int d=0;d<DEG;++d){ e[d] = expf(sc[d]-m); Z += e[d]; }
  float w_[DEG], sw = 0.f;
  #pragma unroll
  for(int d=0;d<DEG;++d){ w_[d] = e[d]/Z*msk[d]; sw += w_[d]; }
  float o = 0.f;
  #pragma unroll
  for(int d=0;d<DEG;++d) o = fmaf(w_[d], nf_s[d][t], o);
  wnf[bl*FP + t] = o;
  if(t==0) swb[bl] = sw;
}

// ======== MFMA path: K3a — ctx = elu(X @ Wat^T + swb*bat) -> bf16 ========
// MODE 0: X = wnf (f32). MODE 1: X = relu(h)*swb computed while staging.
// 64x64 tile, full K=256 in LDS, 4 waves of 32x32.
template<int MODE>
__global__ __launch_bounds__(256) void k_ctx_gemm(
    const float* __restrict__ Xsrc, const float* __restrict__ swb,
    const unsigned short* __restrict__ Wbf, const float* __restrict__ bat,
    unsigned short* __restrict__ ctxbf){
  __shared__ unsigned short A_lds[64][264];   // +8 pad: 2-way bank alias (free)
  __shared__ unsigned short B_lds[64][264];
  const int t = threadIdx.x;
  const int m0 = (blockIdx.x >> 2) * 64, n0 = (blockIdx.x & 3) * 64;
  const int rb = t >> 4, cb = (t & 15) * 16;
  for(int i=0;i<4;++i){
    int row = i*16 + rb;
    const float* src = Xsrc + (size_t)(m0+row)*FP + cb;
    float mult = MODE ? swb[m0+row] : 1.f;
    unsigned short tmp[16];
    #pragma unroll
    for(int q=0;q<4;++q){
      float4 v = ((const float4*)src)[q];
      if(MODE){ v.x=fmaxf(v.x,0.f)*mult; v.y=fmaxf(v.y,0.f)*mult;
                v.z=fmaxf(v.z,0.f)*mult; v.w=fmaxf(v.w,0.f)*mult; }
      tmp[q*4+0]=f2bf(v.x); tmp[q*4+1]=f2bf(v.y); tmp[q*4+2]=f2bf(v.z); tmp[q*4+3]=f2bf(v.w);
    }
    *(s16x8*)&A_lds[row][cb]   = *(s16x8*)&tmp[0];
    *(s16x8*)&A_lds[row][cb+8] = *(s16x8*)&tmp[8];
    const unsigned short* wsrc = Wbf + (size_t)(n0+row)*FP + cb;
    *(s16x8*)&B_lds[row][cb]   = *(const s16x8*)&wsrc[0];
    *(s16x8*)&B_lds[row][cb+8] = *(const s16x8*)&wsrc[8];
  }
  __syncthreads();
  const int w = t>>6, lane = t&63, lr = lane&15, ks = lane>>4;
  const int wr = (w>>1)*32, wc = (w&1)*32;
  f32x4 acc[2][2] = {};
  #pragma unroll
  for(int kk=0;kk<8;++kk){
    int ko = kk*32 + ks*8;
    s16x8 a0 = *(const s16x8*)&A_lds[wr+lr][ko];
    s16x8 a1 = *(const s16x8*)&A_lds[wr+16+lr][ko];
    s16x8 b0 = *(const s16x8*)&B_lds[wc+lr][ko];
    s16x8 b1 = *(const s16x8*)&B_lds[wc+16+lr][ko];
    acc[0][0] = __builtin_amdgcn_mfma_f32_16x16x32_bf16(a0,b0,acc[0][0],0,0,0);
    acc[0][1] = __builtin_amdgcn_mfma_f32_16x16x32_bf16(a0,b1,acc[0][1],0,0,0);
    acc[1][0] = __builtin_amdgcn_mfma_f32_16x16x32_bf16(a1,b0,acc[1][0],0,0,0);
    acc[1][1] = __builtin_amdgcn_mfma_f32_16x16x32_bf16(a1,b1,acc[1][1],0,0,0);
  }
  #pragma unroll
  for(int fm=0;fm<2;++fm){
    #pragma unroll
    for(int fn=0;fn<2;++fn){
      int n = n0 + wc + fn*16 + lr;
      float batv = bat[n];
      #pragma unroll
      for(int j=0;j<4;++j){
        int m = m0 + wr + fm*16 + ks*4 + j;
        float v = acc[fm][fn][j] + swb[m]*batv;
        v = v > 0.f ? v : expm1f(v);
        ctxbf[(size_t)m*FP + n] = f2bf(v);
      }
    }
  }
}

// ======== MFMA path: K3b — all 6 gate GEMM blocks + fused GRU epilogue ========
// tile: 32 rows x 64 h-cols; acc sets {ir,iz,in,hr,hz,hn}; h ping-pong in/out.
__global__ __launch_bounds__(256) void k_gates_gru(
    const unsigned short* __restrict__ ctxbf, const float* __restrict__ h_glob,
    const unsigned short* __restrict__ wihbf, const unsigned short* __restrict__ whhbf,
    const float* __restrict__ bih, const float* __restrict__ bhh,
    float* __restrict__ h_out){
  __shared__ unsigned short A_ctx[32][40];
  __shared__ unsigned short A_h[32][40];
  __shared__ unsigned short B_lds[6][64][40];
  const int t = threadIdx.x;
  const int m0 = (blockIdx.x >> 2) * 32, nc = (blockIdx.x & 3) * 64;
  const int w = t>>6, lane = t&63, lr = lane&15, ks = lane>>4;
  const int mh = (w>>1)*16, nh = (w&1)*32;
  f32x4 acc[6][2] = {};
  for(int kk=0;kk<8;++kk){
    const int k0 = kk*32;
    __syncthreads();
    { // stage A (ctx bf16 direct; h f32->bf16)
      int row = t>>3, c4 = (t&7)*4;
      *(uint2*)&A_ctx[row][c4] = *(const uint2*)(ctxbf + (size_t)(m0+row)*FP + k0 + c4);
      float4 hv = *(const float4*)(h_glob + (size_t)(m0+row)*FP + k0 + c4);
      unsigned short ht[4] = {f2bf(hv.x), f2bf(hv.y), f2bf(hv.z), f2bf(hv.w)};
      *(uint2*)&A_h[row][c4] = *(uint2*)ht;
    }
    #pragma unroll
    for(int i=0;i<6;++i){ // stage B: 6 x 64rows x 32cols bf16
      int idx = i*256 + t;
      int s = idx >> 8, rem = idx & 255;
      int row = rem >> 2, c8 = (rem & 3)*8;
      const unsigned short* wsrc = (s < 3)
          ? wihbf + (size_t)(s*FP + nc + row)*FP + k0 + c8
          : whhbf + (size_t)((s-3)*FP + nc + row)*FP + k0 + c8;
      *(s16x8*)&B_lds[s][row][c8] = *(const s16x8*)wsrc;
    }
    __syncthreads();
    s16x8 ac = *(const s16x8*)&A_ctx[mh+lr][ks*8];
    s16x8 ah = *(const s16x8*)&A_h[mh+lr][ks*8];
    #pragma unroll
    for(int s=0;s<6;++s){
      s16x8 a = (s < 3) ? ac : ah;
      #pragma unroll
      for(int fn=0;fn<2;++fn){
        s16x8 b = *(const s16x8*)&B_lds[s][nh+fn*16+lr][ks*8];
        acc[s][fn] = __builtin_amdgcn_mfma_f32_16x16x32_bf16(a,b,acc[s][fn],0,0,0);
      }
    }
  }
  #pragma unroll
  for(int fn=0;fn<2;++fn){
    int n = nc + nh + fn*16 + lr;
    float bir = bih[n], biz = bih[FP+n], bin_ = bih[2*FP+n];
    float bhr = bhh[n], bhz = bhh[FP+n], bhn  = bhh[2*FP+n];
    #pragma unroll
    for(int j=0;j<4;++j){
      int m = m0 + mh + ks*4 + j;
      float h = h_glob[(size_t)m*FP + n];
      float ir = acc[0][fn][j]+bir, iz = acc[1][fn][j]+biz, inn = acc[2][fn][j]+bin_;
      float hr = acc[3][fn][j]+bhr, hz = acc[4][fn][j]+bhz, hn  = acc[5][fn][j]+bhn;
      float r = 1.f/(1.f + expf(-(ir+hr)));
      float z = 1.f/(1.f + expf(-(iz+hz)));
      float ng = tanhf(inn + r*hn);
      h_out[(size_t)m*FP + n] = (1.f-z)*ng + z*h;
    }
  }
}

// ======== fallback (round-4) fused ctx+GRU, f32 VALU ========
template<int RELUX>
__global__ __launch_bounds__(256) void k_ctx_gru(
    const float* __restrict__ xsrc, const float* __restrict__ swb, float* __restrict__ af,
    const float* __restrict__ Wat, const float* __restrict__ bat,
    const float* __restrict__ wih, const float* __restrict__ whh,
    const float* __restrict__ bih, const float* __restrict__ bhh){
  const int R = 16;
  const int row0 = blockIdx.x * R;
  const int t = threadIdx.x;
  __shared__ __align__(16) float x_s[R][FP];
  __shared__ __align__(16) float h_s[R][FP];
  __shared__ float swb_s[R];
  if(t < R) swb_s[t] = swb[row0 + t];
  __syncthreads();
  #pragma unroll
  for(int r=0;r<R;++r){
    float h = af[(size_t)(row0+r)*FP + t];
    h_s[r][t] = h;
    if(RELUX) x_s[r][t] = fmaxf(h, 0.f) * swb_s[r];
    else      x_s[r][t] = xsrc[(size_t)(row0+r)*FP + t];
  }
  __syncthreads();
  float acc[R];
  #pragma unroll
  for(int r=0;r<R;++r) acc[r] = 0.f;
  const float4* wr = (const float4*)(Wat + (size_t)t*FP);
  for(int k4=0;k4<FP/4;++k4){
    float4 w = wr[k4];
    #pragma unroll
    for(int r=0;r<R;++r){
      float4 xv = ((const float4*)x_s[r])[k4];
      acc[r] = fmaf(xv.x,w.x,acc[r]); acc[r] = fmaf(xv.y,w.y,acc[r]);
      acc[r] = fmaf(xv.z,w.z,acc[r]); acc[r] = fmaf(xv.w,w.w,acc[r]);
    }
  }
  float batv = bat[t];
  float ctx[R];
  #pragma unroll
  for(int r=0;r<R;++r){
    float pre = acc[r] + swb_s[r]*batv;
    ctx[r] = pre > 0.f ? pre : expm1f(pre);
  }
  __syncthreads();
  #pragma unroll
  for(int r=0;r<R;++r) x_s[r][t] = ctx[r];
  __syncthreads();
  float ar_[R], az_[R], an_[R];
  #pragma unroll
  for(int r=0;r<R;++r){ ar_[r]=0.f; az_[r]=0.f; an_[r]=0.f; }
  {
    const float4* p0 = (const float4*)(wih + (size_t)t*FP);
    const float4* p1 = (const float4*)(wih + (size_t)(FP+t)*FP);
    const float4* p2 = (const float4*)(wih + (size_t)(2*FP+t)*FP);
    for(int k4=0;k4<FP/4;++k4){
      float4 w0=p0[k4], w1=p1[k4], w2=p2[k4];
      #pragma unroll
      for(int r=0;r<R;++r){
        float4 xv = ((const float4*)x_s[r])[k4];
        ar_[r]=fmaf(xv.x,w0.x,ar_[r]); ar_[r]=fmaf(xv.y,w0.y,ar_[r]);
        ar_[r]=fmaf(xv.z,w0.z,ar_[r]); ar_[r]=fmaf(xv.w,w0.w,ar_[r]);
        az_[r]=fmaf(xv.x,w1.x,az_[r]); az_[r]=fmaf(xv.y,w1.y,az_[r]);
        az_[r]=fmaf(xv.z,w1.z,az_[r]); az_[r]=fmaf(xv.w,w1.w,az_[r]);
        an_[r]=fmaf(xv.x,w2.x,an_[r]); an_[r]=fmaf(xv.y,w2.y,an_[r]);
        an_[r]=fmaf(xv.z,w2.z,an_[r]); an_[r]=fmaf(xv.w,w2.w,an_[r]);
      }
    }
  }
  float hr_[R], hz_[R], hn_[R];
  #pragma unroll
  for(int r=0;r<R;++r){ hr_[r]=0.f; hz_[r]=0.f; hn_[r]=0.f; }
  {
    const float4* p0 = (const float4*)(whh + (size_t)t*FP);
    const float4* p1 = (const float4*)(whh + (size_t)(FP+t)*FP);
    const float4* p2 = (const float4*)(whh + (size_t)(2*FP+t)*FP);
    for(int k4=0;k4<FP/4;++k4){
      float4 w0=p0[k4], w1=p1[k4], w2=p2[k4];
      #pragma unroll
      for(int r=0;r<R;++r){
        float4 hv = ((const float4*)h_s[r])[k4];
        hr_[r]=fmaf(hv.x,w0.x,hr_[r]); hr_[r]=fmaf(hv.y,w0.y,hr_[r]);
        hr_[r]=fmaf(hv.z,w0.z,hr_[r]); hr_[r]=fmaf(hv.w,w0.w,hr_[r]);
        hz_[r]=fmaf(hv.x,w1.x,hz_[r]); hz_[r]=fmaf(hv.y,w1.y,hz_[r]);
        hz_[r]=fmaf(hv.z,w1.z,hz_[r]); hz_[r]=fmaf(hv.w,w1.w,hz_[r]);
        hn_[r]=fmaf(hv.x,w2.x,hn_[r]); hn_[r]=fmaf(hv.y,w2.y,hn_[r]);
        hn_[r]=fmaf(hv.z,w2.z,hn_[r]); hn_[r]=fmaf(hv.w,w2.w,hn_[r]);
      }
    }
  }
  float bir = bih[t], biz = bih[FP+t], bin_ = bih[2*FP+t];
  float bhr = bhh[t], bhz = bhh[FP+t], bhn  = bhh[2*FP+t];
  #pragma unroll
  for(int r=0;r<R;++r){
    float ir = ar_[r]+bir, iz = az_[r]+biz, inn = an_[r]+bin_;
    float hr = hr_[r]+bhr, hz = hz_[r]+bhz, hn  = hn_[r]+bhn;
    float rg = 1.f/(1.f + expf(-(ir+hr)));
    float zg = 1.f/(1.f + expf(-(iz+hz)));
    float ng = tanhf(inn + rg*hn);
    af[(size_t)(row0+r)*FP + t] = (1.f-zg)*ng + zg*h_s[r][t];
  }
}

// ---- K4: attended_mol = af@maw.T + mab; molfeat = sum relu(af)*mask; emit af f32 ----
__global__ void k_mol_att(const float* __restrict__ af, const float* __restrict__ maw,
    const float* __restrict__ mab, const float* __restrict__ mask,
    float* __restrict__ att, float* __restrict__ molfeat, float* __restrict__ out_af){
  const int b = blockIdx.x, t = threadIdx.x;
  __shared__ __align__(16) float a_s[32][FP];
  __shared__ float msk_s[NL];
  if(t < NL) msk_s[t] = mask[b*NL + t];
  __syncthreads();
  float mf = 0.f;
  const float4* wr = (const float4*)(maw + (size_t)t*FP);
  float mabv = mab[t];
  for(int half=0; half<2; ++half){
    #pragma unroll
    for(int i=0;i<32;++i){
      int l = half*32 + i;
      float v = af[(size_t)(b*NL + l)*FP + t];
      a_s[i][t] = v;
      out_af[(size_t)(b*NL + l)*FP + t] = v;
      mf = fmaf(fmaxf(v,0.f), msk_s[l], mf);
    }
    __syncthreads();
    float acc[32];
    #pragma unroll
    for(int i=0;i<32;++i) acc[i] = 0.f;
    for(int k4=0;k4<FP/4;++k4){
      float4 w = wr[k4];
      #pragma unroll
      for(int i=0;i<32;++i){
        float4 xv = ((const float4*)a_s[i])[k4];
        acc[i] = fmaf(xv.x,w.x,acc[i]); acc[i] = fmaf(xv.y,w.y,acc[i]);
        acc[i] = fmaf(xv.z,w.z,acc[i]); acc[i] = fmaf(xv.w,w.w,acc[i]);
      }
    }
    #pragma unroll
    for(int i=0;i<32;++i) att[(size_t)(b*NL + half*32 + i)*FP + t] = acc[i] + mabv;
    __syncthreads();
  }
  molfeat[b*FP + t] = mf;
}

// ---------------- K5: one mol attention + GRU step ----------------
__global__ void k_mol_step(const float* __restrict__ af, const float* __restrict__ att,
    float* __restrict__ molfeat, const float* __restrict__ maw, const float* __restrict__ mabp,
    const float* __restrict__ mask,
    const float* __restrict__ wih, const float* __restrict__ whh,
    const float* __restrict__ bih, const float* __restrict__ bhh){
  const int b = blockIdx.x, t = threadIdx.x;
  __shared__ __align__(16) float mf_s[FP];
  __shared__ __align__(16) float ctx_s[FP];
  __shared__ float sc_s[NL], aw_s[NL], scr[4];
  mf_s[t] = molfeat[b*FP + t];
  __syncthreads();
  float sa = block_sum256(maw[t]*mf_s[t], scr);
  int l = t >> 2, q = t & 3;
  float p = 0.f;
  {
    const float* ar = af + (size_t)(b*NL + l)*FP + q*64;
    const float* w2 = maw + FP + q*64;
    for(int k=0;k<64;++k) p = fmaf(ar[k], w2[k], p);
  }
  p += __shfl_xor(p, 1, 64);
  p += __shfl_xor(p, 2, 64);
  if(q == 0){
    float mv = mask[b*NL + l];
    float v = sa + p + mabp[0];
    v = v > 0.f ? v : 0.01f*v;
    sc_s[l] = v + (mv == 0.f ? NEGV : 0.f);
  }
  __syncthreads();
  if(t < NL){
    float s = sc_s[t];
    float m = s;
    #pragma unroll
    for(int o=32;o>0;o>>=1) m = fmaxf(m, __shfl_xor(m, o, 64));
    float e = expf(s - m);
    float Z = e;
    #pragma unroll
    for(int o=32;o>0;o>>=1) Z += __shfl_xor(Z, o, 64);
    aw_s[t] = e / Z * mask[b*NL + t];
  }
  __syncthreads();
  float acc = 0.f;
  for(int l2=0;l2<NL;++l2) acc = fmaf(aw_s[l2], att[(size_t)(b*NL + l2)*FP + t], acc);
  ctx_s[t] = acc > 0.f ? acc : expm1f(acc);
  __syncthreads();
  float air=0.f, aiz=0.f, ain=0.f, ahr=0.f, ahz=0.f, ahn=0.f;
  const float4* wirp=(const float4*)(wih + (size_t)t*FP);
  const float4* wizp=(const float4*)(wih + (size_t)(FP+t)*FP);
  const float4* winp=(const float4*)(wih + (size_t)(2*FP+t)*FP);
  const float4* whrp=(const float4*)(whh + (size_t)t*FP);
  const float4* whzp=(const float4*)(whh + (size_t)(FP+t)*FP);
  const float4* whnp=(const float4*)(whh + (size_t)(2*FP+t)*FP);
  for(int k4=0;k4<FP/4;++k4){
    float4 xv = ((const float4*)ctx_s)[k4];
    float4 hv = ((const float4*)mf_s)[k4];
    float4 f0=wirp[k4], f1=wizp[k4], f2=winp[k4];
    float4 g0=whrp[k4], g1=whzp[k4], g2=whnp[k4];
    air=fmaf(xv.x,f0.x,air); air=fmaf(xv.y,f0.y,air); air=fmaf(xv.z,f0.z,air); air=fmaf(xv.w,f0.w,air);
    aiz=fmaf(xv.x,f1.x,aiz); aiz=fmaf(xv.y,f1.y,aiz); aiz=fmaf(xv.z,f1.z,aiz); aiz=fmaf(xv.w,f1.w,aiz);
    ain=fmaf(xv.x,f2.x,ain); ain=fmaf(xv.y,f2.y,ain); ain=fmaf(xv.z,f2.z,ain); ain=fmaf(xv.w,f2.w,ain);
    ahr=fmaf(hv.x,g0.x,ahr); ahr=fmaf(hv.y,g0.y,ahr); ahr=fmaf(hv.z,g0.z,ahr); ahr=fmaf(hv.w,g0.w,ahr);
    ahz=fmaf(hv.x,g1.x,ahz); ahz=fmaf(hv.y,g1.y,ahz); ahz=fmaf(hv.z,g1.z,ahz); ahz=fmaf(hv.w,g1.w,ahz);
    ahn=fmaf(hv.x,g2.x,ahn); ahn=fmaf(hv.y,g2.y,ahn); ahn=fmaf(hv.z,g2.z,ahn); ahn=fmaf(hv.w,g2.w,ahn);
  }
  float ir=air+bih[t], iz=aiz+bih[FP+t], inn=ain+bih[2*FP+t];
  float hr=ahr+bhh[t], hz=ahz+bhh[FP+t], hn=ahn+bhh[2*FP+t];
  float rg = 1.f/(1.f + expf(-(ir+hr)));
  float zg = 1.f/(1.f + expf(-(iz+hz)));
  float ng = tanhf(inn + rg*hn);
  molfeat[b*FP + t] = (1.f-zg)*ng + zg*mf_s[t];
}

// ---------------- K6: mol_prediction ----------------
__global__ void k_out(const float* __restrict__ molfeat, const float* __restrict__ ow,
                      const float* __restrict__ ob, float* __restrict__ outp){
  const int b = blockIdx.x, t = threadIdx.x;
  __shared__ float scr[4];
  float s = block_sum256(molfeat[b*FP + t]*ow[t], scr);
  if(t == 0) outp[b] = s + ob[0];
}

extern "C" void kernel_launch(void* const* d_in, const int* in_sizes, int n_in,
                              void* d_out, int out_size, void* d_ws, size_t ws_size,
                              hipStream_t stream){
  const float* atom_list = (const float*)d_in[0];
  const float* bond_list = (const float*)d_in[1];
  const int*   adl       = (const int*)d_in[2];
  const int*   bdl       = (const int*)d_in[3];
  const float* amask     = (const float*)d_in[4];
  const float* afc_w     = (const float*)d_in[5];
  const float* afc_b     = (const float*)d_in[6];
  const float* nfc_w     = (const float*)d_in[7];
  const float* nfc_b     = (const float*)d_in[8];
  const float* align_w   = (const float*)d_in[9];
  const float* align_b   = (const float*)d_in[10];
  const float* attend_w  = (const float*)d_in[11];
  const float* attend_b  = (const float*)d_in[12];
  const float* gru_wih   = (const float*)d_in[13];
  const float* gru_whh   = (const float*)d_in[14];
  const float* gru_bih   = (const float*)d_in[15];
  const float* gru_bhh   = (const float*)d_in[16];
  const float* mol_align_w  = (const float*)d_in[17];
  const float* mol_align_b  = (const float*)d_in[18];
  const float* mol_attend_w = (const float*)d_in[19];
  const float* mol_attend_b = (const float*)d_in[20];
  const float* mg_wih    = (const float*)d_in[21];
  const float* mg_whh    = (const float*)d_in[22];
  const float* mg_bih    = (const float*)d_in[23];
  const float* mg_bhh    = (const float*)d_in[24];
  const float* out_w     = (const float*)d_in[25];
  const float* out_b     = (const float*)d_in[26];

  float* out_af   = (float*)d_out;
  float* out_pred = out_af + (size_t)NB*NL*FP;

  const size_t NROW = (size_t)NB*NL;          // 16384
  const size_t NEED = NROW*FP*4*3             // af_a, af_b, wnf
                    + NROW*4 + (size_t)NB*FP*4
                    + NROW*FP*2               // ctxbf
                    + (3*FP*FP + 2*3*3*FP*FP)*2;  // bf16 weights

  if(ws_size >= NEED){
    // ---------- MFMA path ----------
    float* af_a   = (float*)d_ws;
    float* af_b   = af_a + NROW*FP;
    float* wnf    = af_b + NROW*FP;            // also mol 'att' later
    float* swb    = wnf  + NROW*FP;
    float* molfeat= swb  + NROW;
    unsigned short* ctxbf  = (unsigned short*)(molfeat + (size_t)NB*FP);
    unsigned short* attw_bf= ctxbf + NROW*FP;
    unsigned short* wih_bf = attw_bf + (size_t)3*FP*FP;
    unsigned short* whh_bf = wih_bf + (size_t)3*3*FP*FP;

    k_cvt<<<(3*FP*FP+255)/256, 256, 0, stream>>>(attend_w, attw_bf, 3*FP*FP);
    k_cvt<<<(9*FP*FP+255)/256, 256, 0, stream>>>(gru_wih, wih_bf, 9*FP*FP);
    k_cvt<<<(9*FP*FP+255)/256, 256, 0, stream>>>(gru_whh, whh_bf, 9*FP*FP);

    k_atom_fc<<<NB*NL, FP, 0, stream>>>(atom_list, afc_w, afc_b, af_a);
    k_nbr_align<<<NB*NL, FP, 0, stream>>>(atom_list, bond_list, adl, bdl,
                                          nfc_w, nfc_b, align_w, align_b, af_a, wnf, swb);
    float* h_cur = af_a;
    float* h_nxt = af_b;
    for(int d=0; d<3; ++d){
      const unsigned short* Wat = attw_bf + (size_t)d*FP*FP;
      const float* bat = attend_b + (size_t)d*FP;
      const unsigned short* wih = wih_bf + (size_t)d*3*FP*FP;
      const unsigned short* whh = whh_bf + (size_t)d*3*FP*FP;
      const float* bih = gru_bih + (size_t)d*3*FP;
      const float* bhh = gru_bhh + (size_t)d*3*FP;
      if(d == 0)
        k_ctx_gemm<0><<<(NB*NL/64)*4, 256, 0, stream>>>(wnf, swb, Wat, bat, ctxbf);
      else
        k_ctx_gemm<1><<<(NB*NL/64)*4, 256, 0, stream>>>(h_cur, swb, Wat, bat, ctxbf);
      k_gates_gru<<<(NB*NL/32)*4, 256, 0, stream>>>(ctxbf, h_cur, wih, whh, bih, bhh, h_nxt);
      float* tmp = h_cur; h_cur = h_nxt; h_nxt = tmp;
    }
    // h_cur now = af after 3 radii (a->b->a->b => af_b)
    k_mol_att<<<NB, FP, 0, stream>>>(h_cur, mol_attend_w, mol_attend_b, amask,
                                     wnf, molfeat, out_af);
    for(int s=0; s<2; ++s)
      k_mol_step<<<NB, FP, 0, stream>>>(h_cur, wnf, molfeat, mol_align_w, mol_align_b, amask,
                                        mg_wih, mg_whh, mg_bih, mg_bhh);
    k_out<<<NB, FP, 0, stream>>>(molfeat, out_w, out_b, out_pred);
  } else {
    // ---------- fallback: round-4 verified f32 path ----------
    float* af      = (float*)d_ws;
    float* wnf     = af  + NROW*FP;
    float* swb     = wnf + NROW*FP;
    float* molfeat = swb + NROW;

    k_atom_fc<<<NB*NL, FP, 0, stream>>>(atom_list, afc_w, afc_b, af);
    k_nbr_align<<<NB*NL, FP, 0, stream>>>(atom_list, bond_list, adl, bdl,
                                          nfc_w, nfc_b, align_w, align_b, af, wnf, swb);
    for(int d=0; d<3; ++d){
      const float* Wat = attend_w + (size_t)d*FP*FP;
      const float* bat = attend_b + (size_t)d*FP;
      const float* wih = gru_wih + (size_t)d*3*FP*FP;
      const float* whh = gru_whh + (size_t)d*3*FP*FP;
      const float* bih = gru_bih + (size_t)d*3*FP;
      const float* bhh = gru_bhh + (size_t)d*3*FP;
      if(d == 0) k_ctx_gru<0><<<NB*NL/16, FP, 0, stream>>>(wnf, swb, af, Wat, bat, wih, whh, bih, bhh);
      else       k_ctx_gru<1><<<NB*NL/16, FP, 0, stream>>>(af,  swb, af, Wat, bat, wih, whh, bih, bhh);
    }
    k_mol_att<<<NB, FP, 0, stream>>>(af, mol_attend_w, mol_attend_b, amask, wnf, molfeat, out_af);
    for(int s=0; s<2; ++s)
      k_mol_step<<<NB, FP, 0, stream>>>(af, wnf, molfeat, mol_align_w, mol_align_b, amask,
                                        mg_wih, mg_whh, mg_bih, mg_bhh);
    k_out<<<NB, FP, 0, stream>>>(molfeat, out_w, out_b, out_pred);
  }
}

// Round 6
// 337.636 us; speedup vs baseline: 5.9240x; 1.8943x over previous
//
#include <hip/hip_runtime.h>
#include <hip/hip_bf16.h>

#define NB 256
#define NL 64
#define DEG 6
#define FEAT 39
#define BOND 10
#define FP 256
#define NEGV (-9.0e8f)

using s16x8 = __attribute__((ext_vector_type(8))) short;
using f32x4 = __attribute__((ext_vector_type(4))) float;

__device__ __forceinline__ unsigned short f2bf(float f){
  unsigned u = __float_as_uint(f);
  u += 0x7fffu + ((u >> 16) & 1u);      // RNE
  return (unsigned short)(u >> 16);
}
__device__ __forceinline__ float lo16(unsigned u){ return __uint_as_float(u << 16); }
__device__ __forceinline__ float hi16(unsigned u){ return __uint_as_float(u & 0xffff0000u); }

__device__ __forceinline__ float block_sum256(float v, float* scr){
  #pragma unroll
  for(int o=32;o>0;o>>=1) v += __shfl_down(v, o, 64);
  __syncthreads();
  if((threadIdx.x & 63) == 0) scr[threadIdx.x >> 6] = v;
  __syncthreads();
  return scr[0] + scr[1] + scr[2] + scr[3];
}
__device__ __forceinline__ float wave_allsum(float v){
  #pragma unroll
  for(int o=1;o<64;o<<=1) v += __shfl_xor(v, o, 64);
  return v;
}

// ---- one-shot converts: 6 f32 weight blobs -> contiguous bf16 region ----
#define CVT_N0 196608   // attend_w 3*256*256
#define CVT_N1 589824   // gru_wih 9*256*256
#define CVT_N2 589824   // gru_whh
#define CVT_N3 65536    // mol_attend_w
#define CVT_N4 196608   // mg_wih 3*256*256
#define CVT_N5 196608   // mg_whh
#define CVT_TOT (CVT_N0+CVT_N1+CVT_N2+CVT_N3+CVT_N4+CVT_N5)  // 1,835,008

__global__ void k_cvt_all(const float* __restrict__ a0, const float* __restrict__ a1,
                          const float* __restrict__ a2, const float* __restrict__ a3,
                          const float* __restrict__ a4, const float* __restrict__ a5,
                          unsigned short* __restrict__ dst){
  int i = blockIdx.x*256 + threadIdx.x;
  int off = i; const float* src;
  if(off < CVT_N0) src = a0;
  else { off -= CVT_N0;
    if(off < CVT_N1) src = a1;
    else { off -= CVT_N1;
      if(off < CVT_N2) src = a2;
      else { off -= CVT_N2;
        if(off < CVT_N3) src = a3;
        else { off -= CVT_N3;
          if(off < CVT_N4) src = a4;
          else { off -= CVT_N4; src = a5; } } } } }
  dst[i] = f2bf(src[off]);
}

// ---- transposes: afc_w [256][39] -> afcT f32 [40][256] (row39=0);
//                  nfc_w [256][49] -> nfcT bf16 [52][256] (rows 49..51 = 0) ----
__global__ void k_tr(const float* __restrict__ aw, const float* __restrict__ nw,
                     float* __restrict__ afcT, unsigned short* __restrict__ nfcT){
  int i = blockIdx.x*256 + threadIdx.x;
  if(i < 40*256){
    int k = i >> 8, r = i & 255;
    afcT[i] = (k < FEAT) ? aw[r*FEAT + k] : 0.f;
  } else {
    int j = i - 40*256;           // < 52*256
    int k = j >> 8, r = j & 255;
    nfcT[j] = (k < FEAT+BOND) ? f2bf(nw[r*(FEAT+BOND) + k]) : (unsigned short)0;
  }
}

// ---- K1: atom FC, 4 atoms/block, wave-per-atom, W^T f32 in LDS ----
__global__ __launch_bounds__(256) void k_atom4(const float* __restrict__ atom,
    const float* __restrict__ afcT, const float* __restrict__ bias, float* __restrict__ af){
  __shared__ float WT[40*256];
  __shared__ float x_s[4][40];
  const int t = threadIdx.x, bl0 = blockIdx.x*4;
  for(int v=t; v<2560; v+=256) *(float4*)&WT[v*4] = *(const float4*)&afcT[v*4];
  for(int idx=t; idx<4*FEAT; idx+=256){ int a=idx/FEAT, k=idx%FEAT; x_s[a][k]=atom[(bl0+a)*FEAT+k]; }
  if(t < 4) x_s[t][39] = 0.f;
  __syncthreads();
  const int w = t>>6, t0 = (t&63)*4, row = bl0 + w;
  float4 b4 = *(const float4*)&bias[t0];
  float acc[4] = {b4.x, b4.y, b4.z, b4.w};
  for(int k=0;k<40;++k){
    float iv = x_s[w][k];
    float4 wv = *(const float4*)&WT[(k<<8)+t0];
    acc[0]=fmaf(iv,wv.x,acc[0]); acc[1]=fmaf(iv,wv.y,acc[1]);
    acc[2]=fmaf(iv,wv.z,acc[2]); acc[3]=fmaf(iv,wv.w,acc[3]);
  }
  float4 o;
  o.x = acc[0]>0.f?acc[0]:0.01f*acc[0]; o.y = acc[1]>0.f?acc[1]:0.01f*acc[1];
  o.z = acc[2]>0.f?acc[2]:0.01f*acc[2]; o.w = acc[3]>0.f?acc[3]:0.01f*acc[3];
  *(float4*)&af[(size_t)row*FP + t0] = o;
}

// ---- K2: neighbor FC + align + softmax + weighted sum. 4 atoms/block, wave-per-atom.
//      nf kept in registers; WnT bf16 in LDS; 2 syncs total. ----
__global__ __launch_bounds__(256) void k_nbr4(const float* __restrict__ atom,
    const float* __restrict__ bond, const int* __restrict__ adl, const int* __restrict__ bdl,
    const unsigned short* __restrict__ nfcT, const float* __restrict__ bn,
    const float* __restrict__ alw, const float* __restrict__ alb,
    const float* __restrict__ af, float* __restrict__ wnf, float* __restrict__ swb){
  __shared__ unsigned short WnT[52*256];     // 26,624 B
  __shared__ float in_s[4][DEG][52];
  __shared__ int   ai_s[4][DEG];
  const int t = threadIdx.x, bl0 = blockIdx.x*4;
  if(t < 24){ int a=t/6, d=t%6; ai_s[a][d] = adl[(bl0+a)*DEG + d]; }
  for(int v=t; v<1664; v+=256) *(s16x8*)&WnT[v*8] = *(const s16x8*)&nfcT[v*8];
  __syncthreads();
  for(int idx=t; idx<4*DEG*(FEAT+BOND); idx+=256){
    int a = idx/(DEG*(FEAT+BOND)), rem = idx%(DEG*(FEAT+BOND));
    int d = rem/(FEAT+BOND), k = rem%(FEAT+BOND);
    int bb = (bl0+a) >> 6;
    float v;
    if(k < FEAT) v = atom[((size_t)bb*NL + ai_s[a][d])*FEAT + k];
    else { int bi = bdl[(bl0+a)*DEG + d]; v = bond[((size_t)bb*NL + bi)*BOND + (k-FEAT)]; }
    in_s[a][d][k] = v;
  }
  if(t < 24){ int a=t/6, d=t%6; in_s[a][d][49]=0.f; in_s[a][d][50]=0.f; in_s[a][d][51]=0.f; }
  __syncthreads();
  const int w = t>>6, lane = t&63, t0 = lane*4, row = bl0 + w;
  float acc[DEG][4] = {};
  for(int k=0;k<52;++k){
    uint2 u = *(const uint2*)&WnT[(k<<8) + t0];
    float w0=lo16(u.x), w1=hi16(u.x), w2=lo16(u.y), w3=hi16(u.y);
    #pragma unroll
    for(int d=0;d<DEG;++d){
      float iv = in_s[w][d][k];
      acc[d][0]=fmaf(iv,w0,acc[d][0]); acc[d][1]=fmaf(iv,w1,acc[d][1]);
      acc[d][2]=fmaf(iv,w2,acc[d][2]); acc[d][3]=fmaf(iv,w3,acc[d][3]);
    }
  }
  float4 bnv = *(const float4*)&bn[t0];
  float bna[4] = {bnv.x, bnv.y, bnv.z, bnv.w};
  float nf[DEG][4];
  #pragma unroll
  for(int d=0;d<DEG;++d)
    #pragma unroll
    for(int j=0;j<4;++j){ float v = acc[d][j] + bna[j]; nf[d][j] = v>0.f ? v : 0.01f*v; }
  // align scores
  float4 af4 = *(const float4*)&af[(size_t)row*FP + t0];
  float4 a1  = *(const float4*)&alw[t0];
  float4 a2  = *(const float4*)&alw[FP + t0];
  float sa = wave_allsum(af4.x*a1.x + af4.y*a1.y + af4.z*a1.z + af4.w*a1.w);
  float sd[DEG];
  #pragma unroll
  for(int d=0;d<DEG;++d)
    sd[d] = wave_allsum(nf[d][0]*a2.x + nf[d][1]*a2.y + nf[d][2]*a2.z + nf[d][3]*a2.w);
  float ab = alb[0];
  float sc[DEG], msk[DEG];
  #pragma unroll
  for(int d=0;d<DEG;++d){
    float v = sa + sd[d] + ab;
    v = v>0.f ? v : 0.01f*v;
    msk[d] = (ai_s[w][d] == NL-1) ? 0.f : 1.f;
    sc[d] = v + (msk[d] > 0.f ? 0.f : NEGV);
  }
  float m = sc[0];
  #pragma unroll
  for(int d=1;d<DEG;++d) m = fmaxf(m, sc[d]);
  float e[DEG], Z = 0.f;
  #pragma unroll
  for(int d=0;d<DEG;++d){ e[d] = expf(sc[d]-m); Z += e[d]; }
  float wgt[DEG], sw = 0.f;
  #pragma unroll
  for(int d=0;d<DEG;++d){ wgt[d] = e[d]/Z*msk[d]; sw += wgt[d]; }
  float o[4] = {};
  #pragma unroll
  for(int d=0;d<DEG;++d)
    #pragma unroll
    for(int j=0;j<4;++j) o[j] = fmaf(wgt[d], nf[d][j], o[j]);
  float4 ov; ov.x=o[0]; ov.y=o[1]; ov.z=o[2]; ov.w=o[3];
  *(float4*)&wnf[(size_t)row*FP + t0] = ov;
  if(lane == 0) swb[row] = sw;
}

// ======== K3a — ctx = elu(X @ Wat^T + swb*bat) -> bf16 (MFMA) ========
template<int MODE>
__global__ __launch_bounds__(256) void k_ctx_gemm(
    const float* __restrict__ Xsrc, const float* __restrict__ swb,
    const unsigned short* __restrict__ Wbf, const float* __restrict__ bat,
    unsigned short* __restrict__ ctxbf){
  __shared__ unsigned short A_lds[64][264];
  __shared__ unsigned short B_lds[64][264];
  const int t = threadIdx.x;
  const int m0 = (blockIdx.x >> 2) * 64, n0 = (blockIdx.x & 3) * 64;
  const int rb = t >> 4, cb = (t & 15) * 16;
  for(int i=0;i<4;++i){
    int row = i*16 + rb;
    const float* src = Xsrc + (size_t)(m0+row)*FP + cb;
    float mult = MODE ? swb[m0+row] : 1.f;
    unsigned short tmp[16];
    #pragma unroll
    for(int q=0;q<4;++q){
      float4 v = ((const float4*)src)[q];
      if(MODE){ v.x=fmaxf(v.x,0.f)*mult; v.y=fmaxf(v.y,0.f)*mult;
                v.z=fmaxf(v.z,0.f)*mult; v.w=fmaxf(v.w,0.f)*mult; }
      tmp[q*4+0]=f2bf(v.x); tmp[q*4+1]=f2bf(v.y); tmp[q*4+2]=f2bf(v.z); tmp[q*4+3]=f2bf(v.w);
    }
    *(s16x8*)&A_lds[row][cb]   = *(s16x8*)&tmp[0];
    *(s16x8*)&A_lds[row][cb+8] = *(s16x8*)&tmp[8];
    const unsigned short* wsrc = Wbf + (size_t)(n0+row)*FP + cb;
    *(s16x8*)&B_lds[row][cb]   = *(const s16x8*)&wsrc[0];
    *(s16x8*)&B_lds[row][cb+8] = *(const s16x8*)&wsrc[8];
  }
  __syncthreads();
  const int w = t>>6, lane = t&63, lr = lane&15, ks = lane>>4;
  const int wr = (w>>1)*32, wc = (w&1)*32;
  f32x4 acc[2][2] = {};
  #pragma unroll
  for(int kk=0;kk<8;++kk){
    int ko = kk*32 + ks*8;
    s16x8 a0 = *(const s16x8*)&A_lds[wr+lr][ko];
    s16x8 a1 = *(const s16x8*)&A_lds[wr+16+lr][ko];
    s16x8 b0 = *(const s16x8*)&B_lds[wc+lr][ko];
    s16x8 b1 = *(const s16x8*)&B_lds[wc+16+lr][ko];
    acc[0][0] = __builtin_amdgcn_mfma_f32_16x16x32_bf16(a0,b0,acc[0][0],0,0,0);
    acc[0][1] = __builtin_amdgcn_mfma_f32_16x16x32_bf16(a0,b1,acc[0][1],0,0,0);
    acc[1][0] = __builtin_amdgcn_mfma_f32_16x16x32_bf16(a1,b0,acc[1][0],0,0,0);
    acc[1][1] = __builtin_amdgcn_mfma_f32_16x16x32_bf16(a1,b1,acc[1][1],0,0,0);
  }
  #pragma unroll
  for(int fm=0;fm<2;++fm)
    #pragma unroll
    for(int fn=0;fn<2;++fn){
      int n = n0 + wc + fn*16 + lr;
      float batv = bat[n];
      #pragma unroll
      for(int j=0;j<4;++j){
        int m = m0 + wr + fm*16 + ks*4 + j;
        float v = acc[fm][fn][j] + swb[m]*batv;
        v = v > 0.f ? v : expm1f(v);
        ctxbf[(size_t)m*FP + n] = f2bf(v);
      }
    }
}

// ======== K3b — 6 gate GEMMs + fused GRU epilogue (MFMA) ========
__global__ __launch_bounds__(256) void k_gates_gru(
    const unsigned short* __restrict__ ctxbf, const float* __restrict__ h_glob,
    const unsigned short* __restrict__ wihbf, const unsigned short* __restrict__ whhbf,
    const float* __restrict__ bih, const float* __restrict__ bhh,
    float* __restrict__ h_out){
  __shared__ unsigned short A_ctx[32][40];
  __shared__ unsigned short A_h[32][40];
  __shared__ unsigned short B_lds[6][64][40];
  const int t = threadIdx.x;
  const int m0 = (blockIdx.x >> 2) * 32, nc = (blockIdx.x & 3) * 64;
  const int w = t>>6, lane = t&63, lr = lane&15, ks = lane>>4;
  const int mh = (w>>1)*16, nh = (w&1)*32;
  f32x4 acc[6][2] = {};
  for(int kk=0;kk<8;++kk){
    const int k0 = kk*32;
    __syncthreads();
    {
      int row = t>>3, c4 = (t&7)*4;
      *(uint2*)&A_ctx[row][c4] = *(const uint2*)(ctxbf + (size_t)(m0+row)*FP + k0 + c4);
      float4 hv = *(const float4*)(h_glob + (size_t)(m0+row)*FP + k0 + c4);
      unsigned short ht[4] = {f2bf(hv.x), f2bf(hv.y), f2bf(hv.z), f2bf(hv.w)};
      *(uint2*)&A_h[row][c4] = *(uint2*)ht;
    }
    #pragma unroll
    for(int i=0;i<6;++i){
      int idx = i*256 + t;
      int s = idx >> 8, rem = idx & 255;
      int row = rem >> 2, c8 = (rem & 3)*8;
      const unsigned short* wsrc = (s < 3)
          ? wihbf + (size_t)(s*FP + nc + row)*FP + k0 + c8
          : whhbf + (size_t)((s-3)*FP + nc + row)*FP + k0 + c8;
      *(s16x8*)&B_lds[s][row][c8] = *(const s16x8*)wsrc;
    }
    __syncthreads();
    s16x8 ac = *(const s16x8*)&A_ctx[mh+lr][ks*8];
    s16x8 ah = *(const s16x8*)&A_h[mh+lr][ks*8];
    #pragma unroll
    for(int s=0;s<6;++s){
      s16x8 a = (s < 3) ? ac : ah;
      #pragma unroll
      for(int fn=0;fn<2;++fn){
        s16x8 b = *(const s16x8*)&B_lds[s][nh+fn*16+lr][ks*8];
        acc[s][fn] = __builtin_amdgcn_mfma_f32_16x16x32_bf16(a,b,acc[s][fn],0,0,0);
      }
    }
  }
  #pragma unroll
  for(int fn=0;fn<2;++fn){
    int n = nc + nh + fn*16 + lr;
    float bir = bih[n], biz = bih[FP+n], bin_ = bih[2*FP+n];
    float bhr = bhh[n], bhz = bhh[FP+n], bhn  = bhh[2*FP+n];
    #pragma unroll
    for(int j=0;j<4;++j){
      int m = m0 + mh + ks*4 + j;
      float h = h_glob[(size_t)m*FP + n];
      float ir = acc[0][fn][j]+bir, iz = acc[1][fn][j]+biz, inn = acc[2][fn][j]+bin_;
      float hr = acc[3][fn][j]+bhr, hz = acc[4][fn][j]+bhz, hn  = acc[5][fn][j]+bhn;
      float r = 1.f/(1.f + expf(-(ir+hr)));
      float z = 1.f/(1.f + expf(-(iz+hz)));
      float ng = tanhf(inn + r*hn);
      h_out[(size_t)m*FP + n] = (1.f-z)*ng + z*h;
    }
  }
}

// ======== K4a — att = X @ W^T + b (f32 out, MFMA) ========
__global__ __launch_bounds__(256) void k_lin_gemm(
    const float* __restrict__ Xsrc, const unsigned short* __restrict__ Wbf,
    const float* __restrict__ bias, float* __restrict__ Y){
  __shared__ unsigned short A_lds[64][264];
  __shared__ unsigned short B_lds[64][264];
  const int t = threadIdx.x;
  const int m0 = (blockIdx.x >> 2) * 64, n0 = (blockIdx.x & 3) * 64;
  const int rb = t >> 4, cb = (t & 15) * 16;
  for(int i=0;i<4;++i){
    int row = i*16 + rb;
    const float* src = Xsrc + (size_t)(m0+row)*FP + cb;
    unsigned short tmp[16];
    #pragma unroll
    for(int q=0;q<4;++q){
      float4 v = ((const float4*)src)[q];
      tmp[q*4+0]=f2bf(v.x); tmp[q*4+1]=f2bf(v.y); tmp[q*4+2]=f2bf(v.z); tmp[q*4+3]=f2bf(v.w);
    }
    *(s16x8*)&A_lds[row][cb]   = *(s16x8*)&tmp[0];
    *(s16x8*)&A_lds[row][cb+8] = *(s16x8*)&tmp[8];
    const unsigned short* wsrc = Wbf + (size_t)(n0+row)*FP + cb;
    *(s16x8*)&B_lds[row][cb]   = *(const s16x8*)&wsrc[0];
    *(s16x8*)&B_lds[row][cb+8] = *(const s16x8*)&wsrc[8];
  }
  __syncthreads();
  const int w = t>>6, lane = t&63, lr = lane&15, ks = lane>>4;
  const int wr = (w>>1)*32, wc = (w&1)*32;
  f32x4 acc[2][2] = {};
  #pragma unroll
  for(int kk=0;kk<8;++kk){
    int ko = kk*32 + ks*8;
    s16x8 a0 = *(const s16x8*)&A_lds[wr+lr][ko];
    s16x8 a1 = *(const s16x8*)&A_lds[wr+16+lr][ko];
    s16x8 b0 = *(const s16x8*)&B_lds[wc+lr][ko];
    s16x8 b1 = *(const s16x8*)&B_lds[wc+16+lr][ko];
    acc[0][0] = __builtin_amdgcn_mfma_f32_16x16x32_bf16(a0,b0,acc[0][0],0,0,0);
    acc[0][1] = __builtin_amdgcn_mfma_f32_16x16x32_bf16(a0,b1,acc[0][1],0,0,0);
    acc[1][0] = __builtin_amdgcn_mfma_f32_16x16x32_bf16(a1,b0,acc[1][0],0,0,0);
    acc[1][1] = __builtin_amdgcn_mfma_f32_16x16x32_bf16(a1,b1,acc[1][1],0,0,0);
  }
  #pragma unroll
  for(int fm=0;fm<2;++fm)
    #pragma unroll
    for(int fn=0;fn<2;++fn){
      int n = n0 + wc + fn*16 + lr;
      float bv = bias[n];
      #pragma unroll
      for(int j=0;j<4;++j){
        int m = m0 + wr + fm*16 + ks*4 + j;
        Y[(size_t)m*FP + n] = acc[fm][fn][j] + bv;
      }
    }
}

// ======== K4b — molfeat = sum relu(af)*mask; emit out_af ========
__global__ void k_finalize(const float* __restrict__ af, const float* __restrict__ mask,
                           float* __restrict__ molfeat, float* __restrict__ out_af){
  const int b = blockIdx.x, t = threadIdx.x;
  __shared__ float msk_s[NL];
  if(t < NL) msk_s[t] = mask[b*NL + t];
  __syncthreads();
  float mf = 0.f;
  for(int l=0;l<NL;++l){
    float v = af[(size_t)(b*NL + l)*FP + t];
    out_af[(size_t)(b*NL + l)*FP + t] = v;
    mf = fmaf(fmaxf(v,0.f), msk_s[l], mf);
  }
  molfeat[b*FP + t] = mf;
}

// ======== K5a — mol attention -> ctx (bf16) ========
__global__ void k_mol_ctx(const float* __restrict__ af, const float* __restrict__ att,
    const float* __restrict__ mfin, const float* __restrict__ maw,
    const float* __restrict__ mabp, const float* __restrict__ mask,
    unsigned short* __restrict__ ctxb){
  const int b = blockIdx.x, t = threadIdx.x;
  __shared__ float mf_s[FP];
  __shared__ float sc_s[NL], aw_s[NL], scr[4];
  mf_s[t] = mfin[b*FP + t];
  __syncthreads();
  float sa = block_sum256(maw[t]*mf_s[t], scr);
  int l = t >> 2, q = t & 3;
  float p = 0.f;
  {
    const float* ar = af + (size_t)(b*NL + l)*FP + q*64;
    const float* w2 = maw + FP + q*64;
    for(int k=0;k<64;++k) p = fmaf(ar[k], w2[k], p);
  }
  p += __shfl_xor(p, 1, 64);
  p += __shfl_xor(p, 2, 64);
  if(q == 0){
    float mv = mask[b*NL + l];
    float v = sa + p + mabp[0];
    v = v > 0.f ? v : 0.01f*v;
    sc_s[l] = v + (mv == 0.f ? NEGV : 0.f);
  }
  __syncthreads();
  if(t < NL){
    float s = sc_s[t];
    float m = s;
    #pragma unroll
    for(int o=32;o>0;o>>=1) m = fmaxf(m, __shfl_xor(m, o, 64));
    float e = expf(s - m);
    float Z = e;
    #pragma unroll
    for(int o=32;o>0;o>>=1) Z += __shfl_xor(Z, o, 64);
    aw_s[t] = e / Z * mask[b*NL + t];
  }
  __syncthreads();
  float acc = 0.f;
  for(int l2=0;l2<NL;++l2) acc = fmaf(aw_s[l2], att[(size_t)(b*NL + l2)*FP + t], acc);
  float c = acc > 0.f ? acc : expm1f(acc);
  ctxb[b*FP + t] = f2bf(c);
}

// ======== K6: mol_prediction ========
__global__ void k_out(const float* __restrict__ molfeat, const float* __restrict__ ow,
                      const float* __restrict__ ob, float* __restrict__ outp){
  const int b = blockIdx.x, t = threadIdx.x;
  __shared__ float scr[4];
  float s = block_sum256(molfeat[b*FP + t]*ow[t], scr);
  if(t == 0) outp[b] = s + ob[0];
}

// ================= fallback (round-4 verified) =================
__global__ void k_atom_fc(const float* __restrict__ atom, const float* __restrict__ W,
                          const float* __restrict__ bias, float* __restrict__ af){
  const int row = blockIdx.x;
  const int t = threadIdx.x;
  __shared__ float x[FEAT];
  if(t < FEAT) x[t] = atom[row*FEAT + t];
  __syncthreads();
  float acc = bias[t];
  const float* wr = W + t*FEAT;
  #pragma unroll
  for(int k=0;k<FEAT;++k) acc = fmaf(x[k], wr[k], acc);
  af[row*FP + t] = acc > 0.f ? acc : 0.01f*acc;
}

__global__ void k_nbr_align(const float* __restrict__ atom, const float* __restrict__ bond,
    const int* __restrict__ adl, const int* __restrict__ bdl,
    const float* __restrict__ Wn, const float* __restrict__ bn,
    const float* __restrict__ alw, const float* __restrict__ alb,
    const float* __restrict__ af, float* __restrict__ wnf, float* __restrict__ swb){
  const int bl = blockIdx.x;
  const int b  = bl >> 6;
  const int t  = threadIdx.x;
  __shared__ float in_s[DEG][FEAT+BOND];
  __shared__ float nf_s[DEG][FP];
  __shared__ float af_s[FP];
  __shared__ int   ai[DEG];
  __shared__ float msk[DEG];
  __shared__ float sc[DEG];
  __shared__ float scr[4];
  if(t < DEG){ int a = adl[bl*DEG + t]; ai[t] = a; msk[t] = (a == NL-1) ? 0.f : 1.f; }
  af_s[t] = af[bl*FP + t];
  __syncthreads();
  for(int idx = t; idx < DEG*(FEAT+BOND); idx += FP){
    int d = idx / (FEAT+BOND), k = idx % (FEAT+BOND);
    float v;
    if(k < FEAT) v = atom[(b*NL + ai[d])*FEAT + k];
    else { int bi = bdl[bl*DEG + d]; v = bond[(b*NL + bi)*BOND + (k-FEAT)]; }
    in_s[d][k] = v;
  }
  __syncthreads();
  float acc[DEG];
  #pragma unroll
  for(int d=0;d<DEG;++d) acc[d] = 0.f;
  const float* wr = Wn + t*(FEAT+BOND);
  for(int k=0;k<FEAT+BOND;++k){
    float w = wr[k];
    #pragma unroll
    for(int d=0;d<DEG;++d) acc[d] = fmaf(in_s[d][k], w, acc[d]);
  }
  float bv = bn[t];
  #pragma unroll
  for(int d=0;d<DEG;++d){
    float v = acc[d] + bv;
    nf_s[d][t] = v > 0.f ? v : 0.01f*v;
  }
  __syncthreads();
  float aw1 = alw[t], aw2 = alw[FP + t];
  float sa = block_sum256(aw1*af_s[t], scr);
  float ab = alb[0];
  for(int d=0;d<DEG;++d){
    float s = block_sum256(aw2*nf_s[d][t], scr);
    if(t==0){
      float v = sa + s + ab;
      v = v > 0.f ? v : 0.01f*v;
      sc[d] = v + (msk[d] > 0.f ? 0.f : NEGV);
    }
  }
  __syncthreads();
  float m = sc[0];
  #pragma unroll
  for(int d=1;d<DEG;++d) m = fmaxf(m, sc[d]);
  float e[DEG], Z = 0.f;
  #pragma unroll
  for(int d=0;d<DEG;++d){ e[d] = expf(sc[d]-m); Z += e[d]; }
  float w_[DEG], sw = 0.f;
  #pragma unroll
  for(int d=0;d<DEG;++d){ w_[d] = e[d]/Z*msk[d]; sw += w_[d]; }
  float o = 0.f;
  #pragma unroll
  for(int d=0;d<DEG;++d) o = fmaf(w_[d], nf_s[d][t], o);
  wnf[bl*FP + t] = o;
  if(t==0) swb[bl] = sw;
}

template<int RELUX>
__global__ __launch_bounds__(256) void k_ctx_gru(
    const float* __restrict__ xsrc, const float* __restrict__ swb, float* __restrict__ af,
    const float* __restrict__ Wat, const float* __restrict__ bat,
    const float* __restrict__ wih, const float* __restrict__ whh,
    const float* __restrict__ bih, const float* __restrict__ bhh){
  const int R = 16;
  const int row0 = blockIdx.x * R;
  const int t = threadIdx.x;
  __shared__ __align__(16) float x_s[R][FP];
  __shared__ __align__(16) float h_s[R][FP];
  __shared__ float swb_s[R];
  if(t < R) swb_s[t] = swb[row0 + t];
  __syncthreads();
  #pragma unroll
  for(int r=0;r<R;++r){
    float h = af[(size_t)(row0+r)*FP + t];
    h_s[r][t] = h;
    if(RELUX) x_s[r][t] = fmaxf(h, 0.f) * swb_s[r];
    else      x_s[r][t] = xsrc[(size_t)(row0+r)*FP + t];
  }
  __syncthreads();
  float acc[R];
  #pragma unroll
  for(int r=0;r<R;++r) acc[r] = 0.f;
  const float4* wr = (const float4*)(Wat + (size_t)t*FP);
  for(int k4=0;k4<FP/4;++k4){
    float4 w = wr[k4];
    #pragma unroll
    for(int r=0;r<R;++r){
      float4 xv = ((const float4*)x_s[r])[k4];
      acc[r] = fmaf(xv.x,w.x,acc[r]); acc[r] = fmaf(xv.y,w.y,acc[r]);
      acc[r] = fmaf(xv.z,w.z,acc[r]); acc[r] = fmaf(xv.w,w.w,acc[r]);
    }
  }
  float batv = bat[t];
  float ctx[R];
  #pragma unroll
  for(int r=0;r<R;++r){
    float pre = acc[r] + swb_s[r]*batv;
    ctx[r] = pre > 0.f ? pre : expm1f(pre);
  }
  __syncthreads();
  #pragma unroll
  for(int r=0;r<R;++r) x_s[r][t] = ctx[r];
  __syncthreads();
  float ar_[R], az_[R], an_[R];
  #pragma unroll
  for(int r=0;r<R;++r){ ar_[r]=0.f; az_[r]=0.f; an_[r]=0.f; }
  {
    const float4* p0 = (const float4*)(wih + (size_t)t*FP);
    const float4* p1 = (const float4*)(wih + (size_t)(FP+t)*FP);
    const float4* p2 = (const float4*)(wih + (size_t)(2*FP+t)*FP);
    for(int k4=0;k4<FP/4;++k4){
      float4 w0=p0[k4], w1=p1[k4], w2=p2[k4];
      #pragma unroll
      for(int r=0;r<R;++r){
        float4 xv = ((const float4*)x_s[r])[k4];
        ar_[r]=fmaf(xv.x,w0.x,ar_[r]); ar_[r]=fmaf(xv.y,w0.y,ar_[r]);
        ar_[r]=fmaf(xv.z,w0.z,ar_[r]); ar_[r]=fmaf(xv.w,w0.w,ar_[r]);
        az_[r]=fmaf(xv.x,w1.x,az_[r]); az_[r]=fmaf(xv.y,w1.y,az_[r]);
        az_[r]=fmaf(xv.z,w1.z,az_[r]); az_[r]=fmaf(xv.w,w1.w,az_[r]);
        an_[r]=fmaf(xv.x,w2.x,an_[r]); an_[r]=fmaf(xv.y,w2.y,an_[r]);
        an_[r]=fmaf(xv.z,w2.z,an_[r]); an_[r]=fmaf(xv.w,w2.w,an_[r]);
      }
    }
  }
  float hr_[R], hz_[R], hn_[R];
  #pragma unroll
  for(int r=0;r<R;++r){ hr_[r]=0.f; hz_[r]=0.f; hn_[r]=0.f; }
  {
    const float4* p0 = (const float4*)(whh + (size_t)t*FP);
    const float4* p1 = (const float4*)(whh + (size_t)(FP+t)*FP);
    const float4* p2 = (const float4*)(whh + (size_t)(2*FP+t)*FP);
    for(int k4=0;k4<FP/4;++k4){
      float4 w0=p0[k4], w1=p1[k4], w2=p2[k4];
      #pragma unroll
      for(int r=0;r<R;++r){
        float4 hv = ((const float4*)h_s[r])[k4];
        hr_[r]=fmaf(hv.x,w0.x,hr_[r]); hr_[r]=fmaf(hv.y,w0.y,hr_[r]);
        hr_[r]=fmaf(hv.z,w0.z,hr_[r]); hr_[r]=fmaf(hv.w,w0.w,hr_[r]);
        hz_[r]=fmaf(hv.x,w1.x,hz_[r]); hz_[r]=fmaf(hv.y,w1.y,hz_[r]);
        hz_[r]=fmaf(hv.z,w1.z,hz_[r]); hz_[r]=fmaf(hv.w,w1.w,hz_[r]);
        hn_[r]=fmaf(hv.x,w2.x,hn_[r]); hn_[r]=fmaf(hv.y,w2.y,hn_[r]);
        hn_[r]=fmaf(hv.z,w2.z,hn_[r]); hn_[r]=fmaf(hv.w,w2.w,hn_[r]);
      }
    }
  }
  float bir = bih[t], biz = bih[FP+t], bin_ = bih[2*FP+t];
  float bhr = bhh[t], bhz = bhh[FP+t], bhn  = bhh[2*FP+t];
  #pragma unroll
  for(int r=0;r<R;++r){
    float ir = ar_[r]+bir, iz = az_[r]+biz, inn = an_[r]+bin_;
    float hr = hr_[r]+bhr, hz = hz_[r]+bhz, hn  = hn_[r]+bhn;
    float rg = 1.f/(1.f + expf(-(ir+hr)));
    float zg = 1.f/(1.f + expf(-(iz+hz)));
    float ng = tanhf(inn + rg*hn);
    af[(size_t)(row0+r)*FP + t] = (1.f-zg)*ng + zg*h_s[r][t];
  }
}

__global__ void k_mol_att(const float* __restrict__ af, const float* __restrict__ maw,
    const float* __restrict__ mab, const float* __restrict__ mask,
    float* __restrict__ att, float* __restrict__ molfeat, float* __restrict__ out_af){
  const int b = blockIdx.x, t = threadIdx.x;
  __shared__ __align__(16) float a_s[32][FP];
  __shared__ float msk_s[NL];
  if(t < NL) msk_s[t] = mask[b*NL + t];
  __syncthreads();
  float mf = 0.f;
  const float4* wr = (const float4*)(maw + (size_t)t*FP);
  float mabv = mab[t];
  for(int half=0; half<2; ++half){
    #pragma unroll
    for(int i=0;i<32;++i){
      int l = half*32 + i;
      float v = af[(size_t)(b*NL + l)*FP + t];
      a_s[i][t] = v;
      out_af[(size_t)(b*NL + l)*FP + t] = v;
      mf = fmaf(fmaxf(v,0.f), msk_s[l], mf);
    }
    __syncthreads();
    float acc[32];
    #pragma unroll
    for(int i=0;i<32;++i) acc[i] = 0.f;
    for(int k4=0;k4<FP/4;++k4){
      float4 w = wr[k4];
      #pragma unroll
      for(int i=0;i<32;++i){
        float4 xv = ((const float4*)a_s[i])[k4];
        acc[i] = fmaf(xv.x,w.x,acc[i]); acc[i] = fmaf(xv.y,w.y,acc[i]);
        acc[i] = fmaf(xv.z,w.z,acc[i]); acc[i] = fmaf(xv.w,w.w,acc[i]);
      }
    }
    #pragma unroll
    for(int i=0;i<32;++i) att[(size_t)(b*NL + half*32 + i)*FP + t] = acc[i] + mabv;
    __syncthreads();
  }
  molfeat[b*FP + t] = mf;
}

__global__ void k_mol_step(const float* __restrict__ af, const float* __restrict__ att,
    float* __restrict__ molfeat, const float* __restrict__ maw, const float* __restrict__ mabp,
    const float* __restrict__ mask,
    const float* __restrict__ wih, const float* __restrict__ whh,
    const float* __restrict__ bih, const float* __restrict__ bhh){
  const int b = blockIdx.x, t = threadIdx.x;
  __shared__ __align__(16) float mf_s[FP];
  __shared__ __align__(16) float ctx_s[FP];
  __shared__ float sc_s[NL], aw_s[NL], scr[4];
  mf_s[t] = molfeat[b*FP + t];
  __syncthreads();
  float sa = block_sum256(maw[t]*mf_s[t], scr);
  int l = t >> 2, q = t & 3;
  float p = 0.f;
  {
    const float* ar = af + (size_t)(b*NL + l)*FP + q*64;
    const float* w2 = maw + FP + q*64;
    for(int k=0;k<64;++k) p = fmaf(ar[k], w2[k], p);
  }
  p += __shfl_xor(p, 1, 64);
  p += __shfl_xor(p, 2, 64);
  if(q == 0){
    float mv = mask[b*NL + l];
    float v = sa + p + mabp[0];
    v = v > 0.f ? v : 0.01f*v;
    sc_s[l] = v + (mv == 0.f ? NEGV : 0.f);
  }
  __syncthreads();
  if(t < NL){
    float s = sc_s[t];
    float m = s;
    #pragma unroll
    for(int o=32;o>0;o>>=1) m = fmaxf(m, __shfl_xor(m, o, 64));
    float e = expf(s - m);
    float Z = e;
    #pragma unroll
    for(int o=32;o>0;o>>=1) Z += __shfl_xor(Z, o, 64);
    aw_s[t] = e / Z * mask[b*NL + t];
  }
  __syncthreads();
  float acc = 0.f;
  for(int l2=0;l2<NL;++l2) acc = fmaf(aw_s[l2], att[(size_t)(b*NL + l2)*FP + t], acc);
  ctx_s[t] = acc > 0.f ? acc : expm1f(acc);
  __syncthreads();
  float air=0.f, aiz=0.f, ain=0.f, ahr=0.f, ahz=0.f, ahn=0.f;
  const float4* wirp=(const float4*)(wih + (size_t)t*FP);
  const float4* wizp=(const float4*)(wih + (size_t)(FP+t)*FP);
  const float4* winp=(const float4*)(wih + (size_t)(2*FP+t)*FP);
  const float4* whrp=(const float4*)(whh + (size_t)t*FP);
  const float4* whzp=(const float4*)(whh + (size_t)(FP+t)*FP);
  const float4* whnp=(const float4*)(whh + (size_t)(2*FP+t)*FP);
  for(int k4=0;k4<FP/4;++k4){
    float4 xv = ((const float4*)ctx_s)[k4];
    float4 hv = ((const float4*)mf_s)[k4];
    float4 f0=wirp[k4], f1=wizp[k4], f2=winp[k4];
    float4 g0=whrp[k4], g1=whzp[k4], g2=whnp[k4];
    air=fmaf(xv.x,f0.x,air); air=fmaf(xv.y,f0.y,air); air=fmaf(xv.z,f0.z,air); air=fmaf(xv.w,f0.w,air);
    aiz=fmaf(xv.x,f1.x,aiz); aiz=fmaf(xv.y,f1.y,aiz); aiz=fmaf(xv.z,f1.z,aiz); aiz=fmaf(xv.w,f1.w,aiz);
    ain=fmaf(xv.x,f2.x,ain); ain=fmaf(xv.y,f2.y,ain); ain=fmaf(xv.z,f2.z,ain); ain=fmaf(xv.w,f2.w,ain);
    ahr=fmaf(hv.x,g0.x,ahr); ahr=fmaf(hv.y,g0.y,ahr); ahr=fmaf(hv.z,g0.z,ahr); ahr=fmaf(hv.w,g0.w,ahr);
    ahz=fmaf(hv.x,g1.x,ahz); ahz=fmaf(hv.y,g1.y,ahz); ahz=fmaf(hv.z,g1.z,ahz); ahz=fmaf(hv.w,g1.w,ahz);
    ahn=fmaf(hv.x,g2.x,ahn); ahn=fmaf(hv.y,g2.y,ahn); ahn=fmaf(hv.z,g2.z,ahn); ahn=fmaf(hv.w,g2.w,ahn);
  }
  float ir=air+bih[t], iz=aiz+bih[FP+t], inn=ain+bih[2*FP+t];
  float hr=ahr+bhh[t], hz=ahz+bhh[FP+t], hn=ahn+bhh[2*FP+t];
  float rg = 1.f/(1.f + expf(-(ir+hr)));
  float zg = 1.f/(1.f + expf(-(iz+hz)));
  float ng = tanhf(inn + rg*hn);
  molfeat[b*FP + t] = (1.f-zg)*ng + zg*mf_s[t];
}

extern "C" void kernel_launch(void* const* d_in, const int* in_sizes, int n_in,
                              void* d_out, int out_size, void* d_ws, size_t ws_size,
                              hipStream_t stream){
  const float* atom_list = (const float*)d_in[0];
  const float* bond_list = (const float*)d_in[1];
  const int*   adl       = (const int*)d_in[2];
  const int*   bdl       = (const int*)d_in[3];
  const float* amask     = (const float*)d_in[4];
  const float* afc_w     = (const float*)d_in[5];
  const float* afc_b     = (const float*)d_in[6];
  const float* nfc_w     = (const float*)d_in[7];
  const float* nfc_b     = (const float*)d_in[8];
  const float* align_w   = (const float*)d_in[9];
  const float* align_b   = (const float*)d_in[10];
  const float* attend_w  = (const float*)d_in[11];
  const float* attend_b  = (const float*)d_in[12];
  const float* gru_wih   = (const float*)d_in[13];
  const float* gru_whh   = (const float*)d_in[14];
  const float* gru_bih   = (const float*)d_in[15];
  const float* gru_bhh   = (const float*)d_in[16];
  const float* mol_align_w  = (const float*)d_in[17];
  const float* mol_align_b  = (const float*)d_in[18];
  const float* mol_attend_w = (const float*)d_in[19];
  const float* mol_attend_b = (const float*)d_in[20];
  const float* mg_wih    = (const float*)d_in[21];
  const float* mg_whh    = (const float*)d_in[22];
  const float* mg_bih    = (const float*)d_in[23];
  const float* mg_bhh    = (const float*)d_in[24];
  const float* out_w     = (const float*)d_in[25];
  const float* out_b     = (const float*)d_in[26];

  float* out_af   = (float*)d_out;
  float* out_pred = out_af + (size_t)NB*NL*FP;

  const size_t NROW = (size_t)NB*NL;          // 16384
  const size_t F32_CNT = 3*NROW*FP + NROW + 2*(size_t)NB*FP + 40*256;
  const size_t BF16_CNT = NROW*FP + CVT_TOT + 52*256;
  const size_t NEED = F32_CNT*4 + BF16_CNT*2;

  if(ws_size >= NEED){
    float* af_a    = (float*)d_ws;
    float* af_b    = af_a + NROW*FP;
    float* wnf     = af_b + NROW*FP;            // nbr ctx source; later mol 'att'
    float* swb     = wnf  + NROW*FP;
    float* mf_a    = swb  + NROW;
    float* mf_b    = mf_a + (size_t)NB*FP;
    float* afcT    = mf_b + (size_t)NB*FP;
    unsigned short* ctxbf   = (unsigned short*)(afcT + 40*256);
    unsigned short* attw_bf = ctxbf + NROW*FP;
    unsigned short* wih_bf  = attw_bf + CVT_N0;
    unsigned short* whh_bf  = wih_bf + CVT_N1;
    unsigned short* maw_bf  = whh_bf + CVT_N2;
    unsigned short* mgih_bf = maw_bf + CVT_N3;
    unsigned short* mghh_bf = mgih_bf + CVT_N4;
    unsigned short* nfcT_bf = mghh_bf + CVT_N5;

    k_cvt_all<<<CVT_TOT/256, 256, 0, stream>>>(attend_w, gru_wih, gru_whh,
                                               mol_attend_w, mg_wih, mg_whh, attw_bf);
    k_tr<<<(40*256 + 52*256)/256, 256, 0, stream>>>(afc_w, nfc_w, afcT, nfcT_bf);

    k_atom4<<<NB*NL/4, 256, 0, stream>>>(atom_list, afcT, afc_b, af_a);
    k_nbr4<<<NB*NL/4, 256, 0, stream>>>(atom_list, bond_list, adl, bdl,
                                        nfcT_bf, nfc_b, align_w, align_b, af_a, wnf, swb);
    float* h_cur = af_a;
    float* h_nxt = af_b;
    for(int d=0; d<3; ++d){
      const unsigned short* Wat = attw_bf + (size_t)d*FP*FP;
      const float* bat = attend_b + (size_t)d*FP;
      const unsigned short* wih = wih_bf + (size_t)d*3*FP*FP;
      const unsigned short* whh = whh_bf + (size_t)d*3*FP*FP;
      const float* bih = gru_bih + (size_t)d*3*FP;
      const float* bhh = gru_bhh + (size_t)d*3*FP;
      if(d == 0)
        k_ctx_gemm<0><<<(NB*NL/64)*4, 256, 0, stream>>>(wnf, swb, Wat, bat, ctxbf);
      else
        k_ctx_gemm<1><<<(NB*NL/64)*4, 256, 0, stream>>>(h_cur, swb, Wat, bat, ctxbf);
      k_gates_gru<<<(NB*NL/32)*4, 256, 0, stream>>>(ctxbf, h_cur, wih, whh, bih, bhh, h_nxt);
      float* tmp = h_cur; h_cur = h_nxt; h_nxt = tmp;
    }
    // h_cur = final atom_feature (af_b after 3 swaps)
    k_lin_gemm<<<(NB*NL/64)*4, 256, 0, stream>>>(h_cur, maw_bf, mol_attend_b, wnf);
    k_finalize<<<NB, 256, 0, stream>>>(h_cur, amask, mf_a, out_af);
    float* m_cur = mf_a; float* m_nxt = mf_b;
    for(int s=0; s<2; ++s){
      k_mol_ctx<<<NB, 256, 0, stream>>>(h_cur, wnf, m_cur, mol_align_w, mol_align_b,
                                        amask, ctxbf);
      k_gates_gru<<<(NB/32)*4, 256, 0, stream>>>(ctxbf, m_cur, mgih_bf, mghh_bf,
                                                 mg_bih, mg_bhh, m_nxt);
      float* tmp = m_cur; m_cur = m_nxt; m_nxt = tmp;
    }
    k_out<<<NB, 256, 0, stream>>>(m_cur, out_w, out_b, out_pred);
  } else {
    // ---------- fallback: round-4 verified f32 path ----------
    float* af      = (float*)d_ws;
    float* wnf     = af  + NROW*FP;
    float* swb     = wnf + NROW*FP;
    float* molfeat = swb + NROW;

    k_atom_fc<<<NB*NL, FP, 0, stream>>>(atom_list, afc_w, afc_b, af);
    k_nbr_align<<<NB*NL, FP, 0, stream>>>(atom_list, bond_list, adl, bdl,
                                          nfc_w, nfc_b, align_w, align_b, af, wnf, swb);
    for(int d=0; d<3; ++d){
      const float* Wat = attend_w + (size_t)d*FP*FP;
      const float* bat = attend_b + (size_t)d*FP;
      const float* wih = gru_wih + (size_t)d*3*FP*FP;
      const float* whh = gru_whh + (size_t)d*3*FP*FP;
      const float* bih = gru_bih + (size_t)d*3*FP;
      const float* bhh = gru_bhh + (size_t)d*3*FP;
      if(d == 0) k_ctx_gru<0><<<NB*NL/16, FP, 0, stream>>>(wnf, swb, af, Wat, bat, wih, whh, bih, bhh);
      else       k_ctx_gru<1><<<NB*NL/16, FP, 0, stream>>>(af,  swb, af, Wat, bat, wih, whh, bih, bhh);
    }
    k_mol_att<<<NB, FP, 0, stream>>>(af, mol_attend_w, mol_attend_b, amask, wnf, molfeat, out_af);
    for(int s=0; s<2; ++s)
      k_mol_step<<<NB, FP, 0, stream>>>(af, wnf, molfeat, mol_align_w, mol_align_b, amask,
                                        mg_wih, mg_whh, mg_bih, mg_bhh);
    k_out<<<NB, FP, 0, stream>>>(molfeat, out_w, out_b, out_pred);
  }
}